// Round 11
// baseline (283.841 us; speedup 1.0000x reference)
//
#include <hip/hip_runtime.h>
#include <hip/hip_bf16.h>

// ---------------------------------------------------------------------------
// GAT (4-layer) on MI355X, bf16 datapath with f32 accumulation.
//   CSR build (zero global atomics, coalesced writes):
//     local_sort -> rtot + rscan -> phaseB LDS counting sort.
//     csrpack[p] = src | dst<<16.
//   prep_kernel: per layer, pack W + ahat=W@a^T into pre-swizzled bf16 image.
//   Per layer:
//     gemm_mfma  (128 rows/block; bf16 MFMA 16x16x32; alpha via extra tile;
//                 hw v_cvt_pk_bf16_f32 for stores)
//     aggregate  (TWO dsts per wave for 2x memory-level parallelism;
//                 wave-synchronous; deferred normalization: stage computes
//                 ew=exp(leaky(as[src]+ad[d])) inline into per-wave LDS;
//                 inner acc += ew*h, dsum += ew; out = elu(acc/dsum + bias))
//   Final: fused pool+FC (batch sorted -> contiguous ranges).
// ---------------------------------------------------------------------------

constexpr int NN     = 50000;
constexpr int NNPAD  = 50048;
constexpr int EE     = 800000;
constexpr int ETOT   = EE + NN;
constexpr int GG     = 128;
constexpr int HIDC   = 32;
constexpr int OUTC   = 64;

constexpr int NRANGE = (NN + 127) / 128;   // 391 dst ranges
constexpr int EPB    = 4096;               // edges per local_sort block
constexpr int NBLK   = (EE + EPB - 1) / EPB;  // 196
constexpr int RCAP   = 2688;               // per-range record capacity

typedef short  bf16x8 __attribute__((ext_vector_type(8)));
typedef float  f32x4  __attribute__((ext_vector_type(4)));

static __device__ __forceinline__ unsigned short f2bf(float f) {
    __hip_bfloat16 h = __float2bfloat16(f);           // hw cvt on gfx950
    unsigned short u; __builtin_memcpy(&u, &h, 2); return u;
}
static __device__ __forceinline__ unsigned int f2bf2(float lo, float hi) {
    __hip_bfloat162 h2 = __float22bfloat162_rn(make_float2(lo, hi));
    unsigned int u; __builtin_memcpy(&u, &h2, 4); return u;
}
static __device__ __forceinline__ float bflo(unsigned int v) {
    return __uint_as_float(v << 16);
}
static __device__ __forceinline__ float bfhi(unsigned int v) {
    return __uint_as_float(v & 0xffff0000u);
}
static __device__ __forceinline__ float elu(float v) {
    return (v > 0.f) ? v : (__expf(v) - 1.f);
}
static __device__ __forceinline__ float leaky(float e) {
    return fmaxf(e, 0.f) + 0.2f * fminf(e, 0.f);
}

// ---------------------------------------------------------------------------
// K1: per-block LDS sort of 4096 edges by dst-range; coalesced output.
__global__ __launch_bounds__(256) void local_sort_kernel(
    const int* __restrict__ ei,
    unsigned int* __restrict__ blocksorted,   // [NBLK*EPB]
    int* __restrict__ boffs)                  // [NBLK*(NRANGE+1)]
{
    __shared__ unsigned int sorted[EPB];
    __shared__ int hist[NRANGE + 1];
    __shared__ int scanv[NRANGE + 1];
    __shared__ int cur[NRANGE + 1];
    __shared__ int wsum4[4];
    __shared__ int ct_s;

    const int b = blockIdx.x, tid = threadIdx.x;
    const int lane = tid & 63, wid = tid >> 6;
    const int e0 = b * EPB;
    const int ecnt = min(EPB, EE - e0);

    for (int t = tid; t < NRANGE + 1; t += 256) hist[t] = 0;
    __syncthreads();

    unsigned int recs[16];
    int rkey[16];
#pragma unroll
    for (int k = 0; k < 16; ++k) {
        const int idx = tid + k * 256;
        rkey[k] = -1;
        if (idx < ecnt) {
            const int src = ei[e0 + idx];
            const int dst = ei[EE + e0 + idx];
            const int r = dst >> 7;
            recs[k] = (unsigned int)src | ((unsigned int)(dst & 127) << 16);
            rkey[k] = r;
            atomicAdd(&hist[r], 1);
        }
    }
    __syncthreads();

    int carry = 0;
    for (int base = 0; base < NRANGE + 1; base += 256) {
        const int i = base + tid;
        const int v = (i < NRANGE + 1) ? hist[i] : 0;
        int incl = v;
#pragma unroll
        for (int off = 1; off < 64; off <<= 1) {
            int t = __shfl_up(incl, off, 64);
            if (lane >= off) incl += t;
        }
        if (lane == 63) wsum4[wid] = incl;
        __syncthreads();
        if (tid == 0) {
            int s = 0;
#pragma unroll
            for (int w = 0; w < 4; ++w) { int t = wsum4[w]; wsum4[w] = s; s += t; }
            ct_s = s;
        }
        __syncthreads();
        const int excl = carry + wsum4[wid] + incl - v;
        if (i < NRANGE + 1) { scanv[i] = excl; cur[i] = excl; }
        carry += ct_s;
        __syncthreads();
    }

#pragma unroll
    for (int k = 0; k < 16; ++k) {
        if (rkey[k] >= 0) {
            const int pos = atomicAdd(&cur[rkey[k]], 1);
            sorted[pos] = recs[k];
        }
    }
    __syncthreads();

    for (int t = tid; t < ecnt; t += 256)
        blocksorted[(size_t)b * EPB + t] = sorted[t];
    for (int t = tid; t < NRANGE + 1; t += 256)
        boffs[b * (NRANGE + 1) + t] = scanv[t];
}

// ---------------------------------------------------------------------------
// K2a: per-range totals (parallel over ranges; one wave per range).
__global__ __launch_bounds__(256) void rtot_kernel(const int* __restrict__ boffs,
                                                   int* __restrict__ rtot)
{
    const int r = blockIdx.x * 4 + (threadIdx.x >> 6);
    const int lane = threadIdx.x & 63;
    if (r >= NRANGE) return;
    int tot = 0;
    for (int b = lane; b < NBLK; b += 64) {
        const int* bp = boffs + b * (NRANGE + 1) + r;
        tot += bp[1] - bp[0];
    }
#pragma unroll
    for (int k = 1; k < 64; k <<= 1) tot += __shfl_xor(tot, k, 64);
    if (lane == 0) rtot[r] = tot + min(128, NN - r * 128);   // + self-loops
}

// K2b: exclusive scan of rtot -> rbase (single small block).
__global__ __launch_bounds__(512) void rscan_kernel(const int* __restrict__ rtot,
                                                    int* __restrict__ rbase)
{
    __shared__ int wsum[8], wpre[8];
    const int tid = threadIdx.x, lane = tid & 63, wid = tid >> 6;
    int tot = (tid < NRANGE) ? rtot[tid] : 0;
    int incl = tot;
#pragma unroll
    for (int off = 1; off < 64; off <<= 1) {
        int t = __shfl_up(incl, off, 64);
        if (lane >= off) incl += t;
    }
    if (lane == 63) wsum[wid] = incl;
    __syncthreads();
    if (tid < 8) {
        int wv = wsum[tid], winc = wv;
#pragma unroll
        for (int off = 1; off < 8; off <<= 1) {
            int t = __shfl_up(winc, off, 64);
            if (tid >= off) winc += t;
        }
        wpre[tid] = winc - wv;
    }
    __syncthreads();
    const int excl = wpre[wid] + incl - tot;
    if (tid < NRANGE) rbase[tid] = excl;
    if (tid == NRANGE - 1) rbase[NRANGE] = excl + tot;
}

// ---------------------------------------------------------------------------
// K3: per-range gather + LDS counting sort -> offs + csrpack (src|dst<<16).
__global__ __launch_bounds__(256) void phaseB_kernel(
    const int* __restrict__ boffs,
    const unsigned int* __restrict__ blocksorted,
    const int* __restrict__ rbase,
    int* __restrict__ offs,
    unsigned int* __restrict__ csrpack)
{
    __shared__ unsigned int rec[RCAP];
    __shared__ unsigned int outpk[RCAP];
    __shared__ int runoff[NBLK + 1];
    __shared__ int bstart[NBLK];
    __shared__ int hist[128], lofs[128], cur[128];
    __shared__ int wsum4[4];
    __shared__ int tot0_s;

    const int r = blockIdx.x, tid = threadIdx.x;
    const int lane = tid & 63, wid = tid >> 6;
    const int base = r * 128;
    const int rn   = min(128, NN - base);

    int cnt = 0;
    if (tid < NBLK) {
        const int* bp = boffs + tid * (NRANGE + 1) + r;
        const int s = bp[0];
        bstart[tid] = s;
        cnt = bp[1] - s;
    }
    if (tid < 128) hist[tid] = 0;
    int incl = cnt;
#pragma unroll
    for (int off = 1; off < 64; off <<= 1) {
        int t = __shfl_up(incl, off, 64);
        if (lane >= off) incl += t;
    }
    if (lane == 63) wsum4[wid] = incl;
    __syncthreads();
    if (tid == 0) {
        int s = 0;
#pragma unroll
        for (int w = 0; w < 4; ++w) { int t = wsum4[w]; wsum4[w] = s; s += t; }
    }
    __syncthreads();
    const int excl = wsum4[wid] + incl - cnt;
    if (tid <= NBLK) runoff[tid] = excl;
    __syncthreads();

    const int tot8 = runoff[NBLK];
    for (int i = tid; i < tot8; i += 256) {
        int lo = 0, hi = NBLK;
        while (lo + 1 < hi) {
            const int mid = (lo + hi) >> 1;
            if (runoff[mid] <= i) lo = mid; else hi = mid;
        }
        rec[i] = blocksorted[(size_t)lo * EPB + bstart[lo] + (i - runoff[lo])];
    }
    for (int t = tid; t < rn; t += 256)                 // self-loops
        rec[tot8 + t] = (unsigned int)(base + t) | ((unsigned int)t << 16);
    const int total = min(tot8 + rn, RCAP);
    __syncthreads();

    for (int t = tid; t < total; t += 256) atomicAdd(&hist[rec[t] >> 16], 1);
    __syncthreads();

    if (tid < 64) {
        int v = hist[tid], incl2 = v;
#pragma unroll
        for (int off = 1; off < 64; off <<= 1) {
            int t = __shfl_up(incl2, off, 64);
            if (tid >= off) incl2 += t;
        }
        lofs[tid] = incl2 - v;
        if (tid == 63) tot0_s = incl2;
    }
    __syncthreads();
    if (tid >= 64 && tid < 128) {
        const int l = tid & 63;
        int v = hist[tid], incl2 = v;
#pragma unroll
        for (int off = 1; off < 64; off <<= 1) {
            int t = __shfl_up(incl2, off, 64);
            if (l >= off) incl2 += t;
        }
        lofs[tid] = tot0_s + incl2 - v;
    }
    __syncthreads();

    if (tid < 128) cur[tid] = lofs[tid];
    if (tid < rn) offs[base + tid] = rbase[r] + lofs[tid];
    if (r == 0 && tid == 0) offs[NN] = rbase[NRANGE];
    __syncthreads();

    for (int t = tid; t < total; t += 256) {
        const unsigned int rc = rec[t];
        const int pos = atomicAdd(&cur[rc >> 16], 1);
        outpk[pos] = (rc & 0xffffu) | ((unsigned int)(base + (rc >> 16)) << 16);
    }
    __syncthreads();
    const int rb = rbase[r];
    for (int t = tid; t < total; t += 256) csrpack[rb + t] = outpk[t];
}

// ---------------------------------------------------------------------------
// prep: per layer, ahat = W@a^T, pack W+ahat into pre-swizzled bf16 image.
__global__ __launch_bounds__(256) void prep_kernel(
    const float* __restrict__ W1, const float* __restrict__ a1s, const float* __restrict__ a1d,
    const float* __restrict__ W2, const float* __restrict__ a2s, const float* __restrict__ a2d,
    const float* __restrict__ W3, const float* __restrict__ a3s, const float* __restrict__ a3d,
    const float* __restrict__ W4, const float* __restrict__ a4s, const float* __restrict__ a4d,
    unsigned short* __restrict__ wtg)        // 4 * 144*128 bf16
{
    __shared__ float ahat_s[128 * 8];
    const int l = blockIdx.x, tid = threadIdx.x;
    const float *W, *as_, *ad_;
    int fo, nh;
    if (l == 0)      { W = W1; as_ = a1s; ad_ = a1d; fo = 128; nh = 4; }
    else if (l == 1) { W = W2; as_ = a2s; ad_ = a2d; fo = 128; nh = 4; }
    else if (l == 2) { W = W3; as_ = a3s; ad_ = a3d; fo = 128; nh = 4; }
    else             { W = W4; as_ = a4s; ad_ = a4d; fo = 32;  nh = 1; }
    const int F_STG = fo + 16;

    for (int item = tid; item < 128 * 8; item += 256) {
        const int k = item >> 3, j = item & 7;
        const int hh = j & 3;
        const bool is_d = j >= 4;
        float v = 0.f;
        if (hh < nh) {
            const float* av = (is_d ? ad_ : as_) + hh * 32;
            const float* wp = W + (size_t)k * fo + hh * 32;
#pragma unroll 8
            for (int c = 0; c < 32; ++c) v = fmaf(wp[c], av[c], v);
        }
        ahat_s[item] = v;
    }
    __syncthreads();

    unsigned short* outb = wtg + (size_t)l * (144 * 128);
    for (int p = tid; p < F_STG * 64; p += 256) {
        const int n  = p % F_STG;
        const int k2 = p / F_STG;
        float w0 = 0.f, w1 = 0.f;
        if (n < fo) {
            w0 = W[(size_t)(2 * k2) * fo + n];
            w1 = W[(size_t)(2 * k2 + 1) * fo + n];
        } else {
            const int j = n - fo;
            if (j < 8) {
                w0 = ahat_s[(2 * k2) * 8 + j];
                w1 = ahat_s[(2 * k2 + 1) * 8 + j];
            }
        }
        const unsigned int packed = f2bf2(w0, w1);
        const int byte = n * 256 + ((4 * k2) ^ ((n & 7) << 4));
        *reinterpret_cast<unsigned int*>(reinterpret_cast<char*>(outb) + byte) = packed;
    }
}

// ---------------------------------------------------------------------------
// hb = x @ W (bf16 MFMA).  128 rows/block (2 row-tiles reuse staged W image).
// XF32: read x as f32 and pack to bf16 in-register (layer 1).
template<int F_OUT, int NH, bool XF32>
__global__ __launch_bounds__(256) void gemm_mfma_kernel(
    const void* __restrict__ xv,
    const unsigned short* __restrict__ wtg,   // prepacked swizzled image
    unsigned short* __restrict__ hb,
    float* __restrict__ as_out, float* __restrict__ ad_out)
{
    constexpr int F_STG = F_OUT + 16;
    __shared__ unsigned short wt[F_STG * 128];
    const int tid = threadIdx.x;

    {
        const bf16x8* __restrict__ wg = reinterpret_cast<const bf16x8*>(wtg);
        bf16x8* wl = reinterpret_cast<bf16x8*>(wt);
        constexpr int NV = F_STG * 16;          // 16B vectors; NV % 256 == 0
#pragma unroll
        for (int i = 0; i < NV / 256; ++i)
            wl[i * 256 + tid] = wg[i * 256 + tid];
    }
    __syncthreads();

    const int wave = tid >> 6, lane = tid & 63;
    const int kchunk = (lane >> 4) * 8;
    const int kb_base = (lane >> 4) * 16;

#pragma unroll
    for (int rr = 0; rr < 2; ++rr) {
        const int row0 = blockIdx.x * 128 + rr * 64 + wave * 16;
        const int arow = row0 + (lane & 15);

        bf16x8 a[4];
        if (XF32) {
            if (arow < NN) {
                const float* __restrict__ ap = (const float*)xv + (size_t)arow * 128;
#pragma unroll
                for (int ks = 0; ks < 4; ++ks) {
                    const float4 f0 = *reinterpret_cast<const float4*>(ap + ks * 32 + kchunk);
                    const float4 f1 = *reinterpret_cast<const float4*>(ap + ks * 32 + kchunk + 4);
                    uint4 u;
                    u.x = f2bf2(f0.x, f0.y);
                    u.y = f2bf2(f0.z, f0.w);
                    u.z = f2bf2(f1.x, f1.y);
                    u.w = f2bf2(f1.z, f1.w);
                    bf16x8 v; __builtin_memcpy(&v, &u, 16);
                    a[ks] = v;
                }
            } else {
#pragma unroll
                for (int ks = 0; ks < 4; ++ks) a[ks] = bf16x8{0,0,0,0,0,0,0,0};
            }
        } else {
            const unsigned short* __restrict__ ap =
                (const unsigned short*)xv + (size_t)arow * 128;
#pragma unroll
            for (int ks = 0; ks < 4; ++ks)
                a[ks] = *reinterpret_cast<const bf16x8*>(ap + ks * 32 + kchunk);
        }

        const int rbase = row0 + (lane >> 4) * 4;

#pragma unroll
        for (int nt = 0; nt < F_OUT / 16; ++nt) {
            const int n = nt * 16 + (lane & 15);
            f32x4 acc = {0.f, 0.f, 0.f, 0.f};
#pragma unroll
            for (int ks = 0; ks < 4; ++ks) {
                const int byte = n * 256 + ((ks * 64 + kb_base) ^ ((n & 7) << 4));
                bf16x8 b = *reinterpret_cast<const bf16x8*>(
                    reinterpret_cast<const char*>(wt) + byte);
                acc = __builtin_amdgcn_mfma_f32_16x16x32_bf16(a[ks], b, acc, 0, 0, 0);
            }
#pragma unroll
            for (int r = 0; r < 4; ++r) {
                const int row = rbase + r;
                if (row < NN)
                    hb[(size_t)row * F_OUT + n] = f2bf(acc[r]);
            }
        }

        // ---- alpha tile ----
        {
            const int n = F_OUT + (lane & 15);
            f32x4 acc = {0.f, 0.f, 0.f, 0.f};
#pragma unroll
            for (int ks = 0; ks < 4; ++ks) {
                const int byte = n * 256 + ((ks * 64 + kb_base) ^ ((n & 7) << 4));
                bf16x8 b = *reinterpret_cast<const bf16x8*>(
                    reinterpret_cast<const char*>(wt) + byte);
                acc = __builtin_amdgcn_mfma_f32_16x16x32_bf16(a[ks], b, acc, 0, 0, 0);
            }
            const int col = lane & 15;
            if (col < 8) {
                const int hh = col & 3;
                const bool is_d = col >= 4;
                if (hh < NH) {
                    float* op = is_d ? ad_out : as_out;
#pragma unroll
                    for (int r = 0; r < 4; ++r) {
                        const int row = rbase + r;
                        if (row < NN) {
                            if (NH == 4) op[row * 4 + hh] = acc[r];
                            else         op[row]          = acc[r];
                        }
                    }
                }
            }
        }
    }
}

// ---------------------------------------------------------------------------
// Aggregate helpers (wave-synchronous, per-wave LDS slices).
template<int HEADS>
static __device__ __forceinline__ void agg_stage(
    const unsigned int* __restrict__ csrpack, const float* __restrict__ as_,
    const float* __restrict__ ad_h,
    float* __restrict__ w_lds, int* __restrict__ src_lds,
    int lane, int p0, int end)
{
    const int p = p0 + lane;
    const unsigned int pk = (p < end) ? csrpack[p] : 0u;
    const int src = (int)(pk & 0xffffu);
    src_lds[lane] = src;
    if (HEADS == 4) {
        float4 w4 = make_float4(0.f, 0.f, 0.f, 0.f);
        if (p < end) {
            const float4 s4 = *reinterpret_cast<const float4*>(as_ + (size_t)src * 4);
            w4.x = __expf(leaky(s4.x + ad_h[0]));
            w4.y = __expf(leaky(s4.y + ad_h[1]));
            w4.z = __expf(leaky(s4.z + ad_h[2]));
            w4.w = __expf(leaky(s4.w + ad_h[3]));
        }
        *reinterpret_cast<float4*>(w_lds + lane * 4) = w4;
    } else {
        float w1 = 0.f;
        if (p < end) w1 = __expf(leaky(as_[src] + ad_h[0]));
        w_lds[lane] = w1;
    }
}

template<int F_OUT>
static __device__ __forceinline__ void agg_inner(
    const unsigned short* __restrict__ hlin,
    const float* __restrict__ w_lds, const int* __restrict__ src_lds,
    int cnt, int q, int cl, int hd, float acc[8], float& dsum)
{
    if (F_OUT == 128) {
        const int cntR = (cnt + 3) & ~3;
#pragma unroll 4
        for (int j = 0; j < cntR; j += 4) {
            const int   slot = j + q;
            const int   srcj = src_lds[slot];
            const float w    = w_lds[slot * 4 + hd];
            const uint4 hv   = *reinterpret_cast<const uint4*>(
                hlin + (size_t)srcj * 128 + cl * 8);
            dsum += w;
            acc[0] = fmaf(w, bflo(hv.x), acc[0]);
            acc[1] = fmaf(w, bfhi(hv.x), acc[1]);
            acc[2] = fmaf(w, bflo(hv.y), acc[2]);
            acc[3] = fmaf(w, bfhi(hv.y), acc[3]);
            acc[4] = fmaf(w, bflo(hv.z), acc[4]);
            acc[5] = fmaf(w, bfhi(hv.z), acc[5]);
            acc[6] = fmaf(w, bflo(hv.w), acc[6]);
            acc[7] = fmaf(w, bfhi(hv.w), acc[7]);
        }
    } else {
        const int cntR = (cnt + 15) & ~15;
#pragma unroll 4
        for (int j = 0; j < cntR; j += 16) {
            const int   slot = j + q;
            const int   srcj = src_lds[slot];
            const float w    = w_lds[slot];
            const uint4 hv   = *reinterpret_cast<const uint4*>(
                hlin + (size_t)srcj * 32 + cl * 8);
            dsum += w;
            acc[0] = fmaf(w, bflo(hv.x), acc[0]);
            acc[1] = fmaf(w, bfhi(hv.x), acc[1]);
            acc[2] = fmaf(w, bflo(hv.y), acc[2]);
            acc[3] = fmaf(w, bfhi(hv.y), acc[3]);
            acc[4] = fmaf(w, bflo(hv.z), acc[4]);
            acc[5] = fmaf(w, bfhi(hv.z), acc[5]);
            acc[6] = fmaf(w, bflo(hv.w), acc[6]);
            acc[7] = fmaf(w, bfhi(hv.w), acc[7]);
        }
    }
}

template<int F_OUT, bool OUT_BF16>
static __device__ __forceinline__ void agg_epilogue(
    float acc[8], float dsum, int lane, int d,
    const float* __restrict__ bias, void* __restrict__ out_v)
{
    if (F_OUT == 128) {
#pragma unroll
        for (int t = 0; t < 8; ++t) {
            acc[t] += __shfl_xor(acc[t], 16, 64);
            acc[t] += __shfl_xor(acc[t], 32, 64);
        }
        dsum += __shfl_xor(dsum, 16, 64);
        dsum += __shfl_xor(dsum, 32, 64);
        if (lane < 16) {
            const float rinv = 1.f / (dsum + 1e-16f);
            const int c0 = lane * 8;
            float v[8];
#pragma unroll
            for (int t = 0; t < 8; ++t) v[t] = elu(fmaf(acc[t], rinv, bias[c0 + t]));
            uint4 pk;
            pk.x = f2bf2(v[0], v[1]);
            pk.y = f2bf2(v[2], v[3]);
            pk.z = f2bf2(v[4], v[5]);
            pk.w = f2bf2(v[6], v[7]);
            *reinterpret_cast<uint4*>((unsigned short*)out_v + (size_t)d * 128 + c0) = pk;
        }
    } else {
#pragma unroll
        for (int t = 0; t < 8; ++t) {
            acc[t] += __shfl_xor(acc[t], 4, 64);
            acc[t] += __shfl_xor(acc[t], 8, 64);
            acc[t] += __shfl_xor(acc[t], 16, 64);
            acc[t] += __shfl_xor(acc[t], 32, 64);
        }
        dsum += __shfl_xor(dsum, 4, 64);
        dsum += __shfl_xor(dsum, 8, 64);
        dsum += __shfl_xor(dsum, 16, 64);
        dsum += __shfl_xor(dsum, 32, 64);
        if (lane < 4) {
            const float rinv = 1.f / (dsum + 1e-16f);
            const int c0 = lane * 8;
            float v[8];
#pragma unroll
            for (int t = 0; t < 8; ++t) v[t] = elu(fmaf(acc[t], rinv, bias[c0 + t]));
            float* op = (float*)out_v + (size_t)d * 32 + c0;
            *reinterpret_cast<float4*>(op)     = make_float4(v[0], v[1], v[2], v[3]);
            *reinterpret_cast<float4*>(op + 4) = make_float4(v[4], v[5], v[6], v[7]);
        }
    }
}

// ---------------------------------------------------------------------------
// Per-dst aggregation: TWO dsts per wave (2x MLP), 4 waves per block.
// Deferred normalization; inline edge weights; wave-synchronous.
template<int HEADS, int F_OUT, bool OUT_BF16>
__global__ __launch_bounds__(256) void aggregate_kernel(
    const unsigned short* __restrict__ hlin,
    const float* __restrict__ as_,
    const float* __restrict__ ad_,
    const int* __restrict__ offs,
    const unsigned int* __restrict__ csrpack,
    const float* __restrict__ bias,
    void* __restrict__ out_v)
{
    __shared__ float w_all[8][64 * HEADS];
    __shared__ int   s_all[8][64];
    const int wave = threadIdx.x >> 6;
    const int lane = threadIdx.x & 63;
    const int d0   = blockIdx.x * 8 + wave * 2;   // grid covers exactly NN (even)
    const int d1   = d0 + 1;
    float* __restrict__ w0 = w_all[wave * 2];
    float* __restrict__ w1 = w_all[wave * 2 + 1];
    int*   __restrict__ s0 = s_all[wave * 2];
    int*   __restrict__ s1 = s_all[wave * 2 + 1];

    const int beg0 = offs[d0];
    const int end0 = offs[d1];
    const int end1 = offs[d1 + 1];

    float ad0[HEADS], ad1[HEADS];
#pragma unroll
    for (int h = 0; h < HEADS; ++h) {
        ad0[h] = ad_[d0 * HEADS + h];
        ad1[h] = ad_[d1 * HEADS + h];
    }

    float acc0[8] = {0,0,0,0,0,0,0,0};
    float acc1[8] = {0,0,0,0,0,0,0,0};
    float dsum0 = 0.f, dsum1 = 0.f;
    const int q  = (F_OUT == 128) ? (lane >> 4) : (lane >> 2);
    const int cl = (F_OUT == 128) ? (lane & 15) : (lane & 3);
    const int hd = (F_OUT == 128) ? (cl >> 2) : 0;

    int b0 = beg0, b1 = end0;   // d1's edges start at end0
    while (b0 < end0 || b1 < end1) {
        if (b0 < end0) agg_stage<HEADS>(csrpack, as_, ad0, w0, s0, lane, b0, end0);
        if (b1 < end1) agg_stage<HEADS>(csrpack, as_, ad1, w1, s1, lane, b1, end1);
        asm volatile("s_waitcnt lgkmcnt(0)" ::: "memory");
        if (b0 < end0) {
            agg_inner<F_OUT>(hlin, w0, s0, min(64, end0 - b0), q, cl, hd, acc0, dsum0);
            b0 += 64;
        }
        if (b1 < end1) {
            agg_inner<F_OUT>(hlin, w1, s1, min(64, end1 - b1), q, cl, hd, acc1, dsum1);
            b1 += 64;
        }
    }

    agg_epilogue<F_OUT, OUT_BF16>(acc0, dsum0, lane, d0, bias, out_v);
    agg_epilogue<F_OUT, OUT_BF16>(acc1, dsum1, lane, d1, bias, out_v);
}

// ---------------------------------------------------------------------------
__global__ __launch_bounds__(256) void pool_fc_kernel(
    const float* __restrict__ h4, const int* __restrict__ batch,
    const float* __restrict__ fcW, const float* __restrict__ fcb,
    float* __restrict__ out)
{
    const int g = blockIdx.x;
    __shared__ int sb, se;
    if (threadIdx.x == 0) {
        int lo = 0, hi = NN;
        while (lo < hi) { int mid = (lo + hi) >> 1; if (batch[mid] < g) lo = mid + 1; else hi = mid; }
        sb = lo;
        lo = sb; hi = NN;
        while (lo < hi) { int mid = (lo + hi) >> 1; if (batch[mid] < g + 1) lo = mid + 1; else hi = mid; }
        se = lo;
    }
    __syncthreads();
    const int s = sb, e = se;

    const int c  = threadIdx.x & 31;
    const int rg = threadIdx.x >> 5;
    float acc = 0.f;
    for (int n = s + rg; n < e; n += 8)
        acc += h4[(size_t)n * HIDC + c];

    __shared__ float red[8][32];
    red[rg][c] = acc;
    __syncthreads();
    __shared__ float pooled_s[32];
    if (threadIdx.x < 32) {
        float v = 0.f;
#pragma unroll
        for (int r = 0; r < 8; ++r) v += red[r][threadIdx.x];
        pooled_s[threadIdx.x] = v / fmaxf((float)(e - s), 1.f);
    }
    __syncthreads();
    if (threadIdx.x < OUTC) {
        const int o = threadIdx.x;
        float a2 = fcb[o];
#pragma unroll
        for (int cc = 0; cc < HIDC; ++cc)
            a2 = fmaf(pooled_s[cc], fcW[cc * OUTC + o], a2);
        out[g * OUTC + o] = a2;
    }
}

// ---------------------------------------------------------------------------
extern "C" void kernel_launch(void* const* d_in, const int* in_sizes, int n_in,
                              void* d_out, int out_size, void* d_ws, size_t ws_size,
                              hipStream_t stream)
{
    const float* x     = (const float*)d_in[0];
    const int*   ei    = (const int*)d_in[1];
    const int*   batch = (const int*)d_in[2];
    const float* W1  = (const float*)d_in[3];
    const float* a1s = (const float*)d_in[4];
    const float* a1d = (const float*)d_in[5];
    const float* b1  = (const float*)d_in[6];
    const float* W2  = (const float*)d_in[7];
    const float* a2s = (const float*)d_in[8];
    const float* a2d = (const float*)d_in[9];
    const float* b2  = (const float*)d_in[10];
    const float* W3  = (const float*)d_in[11];
    const float* a3s = (const float*)d_in[12];
    const float* a3d = (const float*)d_in[13];
    const float* b3  = (const float*)d_in[14];
    const float* W4  = (const float*)d_in[15];
    const float* a4s = (const float*)d_in[16];
    const float* a4d = (const float*)d_in[17];
    const float* b4  = (const float*)d_in[18];
    const float* fcW = (const float*)d_in[19];
    const float* fcb = (const float*)d_in[20];
    float* out = (float*)d_out;

    // workspace layout (overlays: blocksorted aliases hb; bufF aliases xb)
    unsigned short* xb = (unsigned short*)d_ws;                 // NNPAD*128 bf16
    unsigned short* hb = xb + (size_t)NNPAD * 128;              // NNPAD*128 bf16
    float* asb  = (float*)(hb + (size_t)NNPAD * 128);           // N*4
    float* adb  = asb + (size_t)NN * 4;                         // N*4
    int*   offs    = (int*)(adb + (size_t)NN * 4);              // N+1
    unsigned int* csrpack = (unsigned int*)(offs + NN + 1);     // E+N (src|dst<<16)
    int*   boffs  = (int*)(csrpack + ETOT);                     // NBLK*(NRANGE+1)
    int*   rbase  = boffs + NBLK * (NRANGE + 1);                // NRANGE+1
    int*   rtot   = rbase + NRANGE + 1;                         // NRANGE
    unsigned short* wtg = (unsigned short*)(rtot + NRANGE);     // 4*144*128 bf16
    unsigned int* blocksorted = (unsigned int*)hb;              // NBLK*EPB (alias)
    float* bufF = (float*)xb;                                   // N*32 f32 (alias)

    // ---- CSR build ----
    local_sort_kernel<<<NBLK, 256, 0, stream>>>(ei, blocksorted, boffs);
    rtot_kernel<<<(NRANGE + 3) / 4, 256, 0, stream>>>(boffs, rtot);
    rscan_kernel<<<1, 512, 0, stream>>>(rtot, rbase);
    phaseB_kernel<<<NRANGE, 256, 0, stream>>>(boffs, blocksorted, rbase, offs, csrpack);

    // ---- prep (W+ahat -> prepacked bf16 swizzled images) ----
    prep_kernel<<<4, 256, 0, stream>>>(W1, a1s, a1d, W2, a2s, a2d,
                                       W3, a3s, a3d, W4, a4s, a4d, wtg);

    constexpr int GEMM_GRID = NNPAD / 128;      // 391
    constexpr int AGG_GRID  = NN / 8;           // 6250 (2 dsts/wave, 4 waves)
    constexpr size_t WSTRIDE = 144 * 128;

    // ---- layer 1 (reads x f32 directly) ----
    gemm_mfma_kernel<128, 4, true><<<GEMM_GRID, 256, 0, stream>>>(x, wtg + 0 * WSTRIDE, hb, asb, adb);
    aggregate_kernel<4, 128, true><<<AGG_GRID, 256, 0, stream>>>(hb, asb, adb, offs, csrpack, b1, xb);
    // ---- layer 2 ----
    gemm_mfma_kernel<128, 4, false><<<GEMM_GRID, 256, 0, stream>>>(xb, wtg + 1 * WSTRIDE, hb, asb, adb);
    aggregate_kernel<4, 128, true><<<AGG_GRID, 256, 0, stream>>>(hb, asb, adb, offs, csrpack, b2, xb);
    // ---- layer 3 ----
    gemm_mfma_kernel<128, 4, false><<<GEMM_GRID, 256, 0, stream>>>(xb, wtg + 2 * WSTRIDE, hb, asb, adb);
    aggregate_kernel<4, 128, true><<<AGG_GRID, 256, 0, stream>>>(hb, asb, adb, offs, csrpack, b3, xb);
    // ---- layer 4 (heads=1, 32 ch, f32 out) ----
    gemm_mfma_kernel<32, 1, false><<<GEMM_GRID, 256, 0, stream>>>(xb, wtg + 3 * WSTRIDE, hb, asb, adb);
    aggregate_kernel<1, 32, false><<<AGG_GRID, 256, 0, stream>>>(hb, asb, adb, offs, csrpack, b4, bufF);

    // ---- fused mean pool + FC ----
    pool_fc_kernel<<<GG, 256, 0, stream>>>(bufF, batch, fcW, fcb, out);
}

// Round 12
// 258.101 us; speedup vs baseline: 1.0997x; 1.0997x over previous
//
#include <hip/hip_runtime.h>
#include <hip/hip_bf16.h>

// ---------------------------------------------------------------------------
// GAT (4-layer) on MI355X, bf16 datapath with f32 accumulation.
//   CSR build (zero global atomics, coalesced writes):
//     local_sort -> rtot + rscan -> phaseB LDS counting sort.
//     csrpack[p] = src | dst<<16.
//   prep_kernel: per layer, pack W + ahat=W@a^T into pre-swizzled bf16 image.
//   Per layer:
//     gemm_mfma  (128 rows/block; bf16 MFMA 16x16x32; alpha via extra tile;
//                 hw v_cvt_pk_bf16_f32 conversions)
//     aggregate  (1 dst/wave, 4 waves/block; wave-synchronous; deferred
//                 normalization: stage computes ew=exp(leaky(as[src]+ad[d]))
//                 inline into per-wave LDS; inner acc += ew*h, dsum += ew;
//                 epilogue out = elu(acc/dsum + bias); uint4 gathers 8ch/lane)
//   Final: fused pool+FC (batch sorted -> contiguous ranges).
// ---------------------------------------------------------------------------

constexpr int NN     = 50000;
constexpr int NNPAD  = 50048;
constexpr int EE     = 800000;
constexpr int ETOT   = EE + NN;
constexpr int GG     = 128;
constexpr int HIDC   = 32;
constexpr int OUTC   = 64;

constexpr int NRANGE = (NN + 127) / 128;   // 391 dst ranges
constexpr int EPB    = 4096;               // edges per local_sort block
constexpr int NBLK   = (EE + EPB - 1) / EPB;  // 196
constexpr int RCAP   = 2688;               // per-range record capacity

typedef short  bf16x8 __attribute__((ext_vector_type(8)));
typedef float  f32x4  __attribute__((ext_vector_type(4)));

static __device__ __forceinline__ unsigned short f2bf(float f) {
    __hip_bfloat16 h = __float2bfloat16(f);           // hw cvt on gfx950
    unsigned short u; __builtin_memcpy(&u, &h, 2); return u;
}
static __device__ __forceinline__ unsigned int f2bf2(float lo, float hi) {
    __hip_bfloat162 h2 = __float22bfloat162_rn(make_float2(lo, hi));
    unsigned int u; __builtin_memcpy(&u, &h2, 4); return u;
}
static __device__ __forceinline__ float bflo(unsigned int v) {
    return __uint_as_float(v << 16);
}
static __device__ __forceinline__ float bfhi(unsigned int v) {
    return __uint_as_float(v & 0xffff0000u);
}
static __device__ __forceinline__ float elu(float v) {
    return (v > 0.f) ? v : (__expf(v) - 1.f);
}
static __device__ __forceinline__ float leaky(float e) {
    return fmaxf(e, 0.f) + 0.2f * fminf(e, 0.f);
}

// ---------------------------------------------------------------------------
// K1: per-block LDS sort of 4096 edges by dst-range; coalesced output.
__global__ __launch_bounds__(256) void local_sort_kernel(
    const int* __restrict__ ei,
    unsigned int* __restrict__ blocksorted,   // [NBLK*EPB]
    int* __restrict__ boffs)                  // [NBLK*(NRANGE+1)]
{
    __shared__ unsigned int sorted[EPB];
    __shared__ int hist[NRANGE + 1];
    __shared__ int scanv[NRANGE + 1];
    __shared__ int cur[NRANGE + 1];
    __shared__ int wsum4[4];
    __shared__ int ct_s;

    const int b = blockIdx.x, tid = threadIdx.x;
    const int lane = tid & 63, wid = tid >> 6;
    const int e0 = b * EPB;
    const int ecnt = min(EPB, EE - e0);

    for (int t = tid; t < NRANGE + 1; t += 256) hist[t] = 0;
    __syncthreads();

    unsigned int recs[16];
    int rkey[16];
#pragma unroll
    for (int k = 0; k < 16; ++k) {
        const int idx = tid + k * 256;
        rkey[k] = -1;
        if (idx < ecnt) {
            const int src = ei[e0 + idx];
            const int dst = ei[EE + e0 + idx];
            const int r = dst >> 7;
            recs[k] = (unsigned int)src | ((unsigned int)(dst & 127) << 16);
            rkey[k] = r;
            atomicAdd(&hist[r], 1);
        }
    }
    __syncthreads();

    int carry = 0;
    for (int base = 0; base < NRANGE + 1; base += 256) {
        const int i = base + tid;
        const int v = (i < NRANGE + 1) ? hist[i] : 0;
        int incl = v;
#pragma unroll
        for (int off = 1; off < 64; off <<= 1) {
            int t = __shfl_up(incl, off, 64);
            if (lane >= off) incl += t;
        }
        if (lane == 63) wsum4[wid] = incl;
        __syncthreads();
        if (tid == 0) {
            int s = 0;
#pragma unroll
            for (int w = 0; w < 4; ++w) { int t = wsum4[w]; wsum4[w] = s; s += t; }
            ct_s = s;
        }
        __syncthreads();
        const int excl = carry + wsum4[wid] + incl - v;
        if (i < NRANGE + 1) { scanv[i] = excl; cur[i] = excl; }
        carry += ct_s;
        __syncthreads();
    }

#pragma unroll
    for (int k = 0; k < 16; ++k) {
        if (rkey[k] >= 0) {
            const int pos = atomicAdd(&cur[rkey[k]], 1);
            sorted[pos] = recs[k];
        }
    }
    __syncthreads();

    for (int t = tid; t < ecnt; t += 256)
        blocksorted[(size_t)b * EPB + t] = sorted[t];
    for (int t = tid; t < NRANGE + 1; t += 256)
        boffs[b * (NRANGE + 1) + t] = scanv[t];
}

// ---------------------------------------------------------------------------
// K2a: per-range totals (parallel over ranges; one wave per range).
__global__ __launch_bounds__(256) void rtot_kernel(const int* __restrict__ boffs,
                                                   int* __restrict__ rtot)
{
    const int r = blockIdx.x * 4 + (threadIdx.x >> 6);
    const int lane = threadIdx.x & 63;
    if (r >= NRANGE) return;
    int tot = 0;
    for (int b = lane; b < NBLK; b += 64) {
        const int* bp = boffs + b * (NRANGE + 1) + r;
        tot += bp[1] - bp[0];
    }
#pragma unroll
    for (int k = 1; k < 64; k <<= 1) tot += __shfl_xor(tot, k, 64);
    if (lane == 0) rtot[r] = tot + min(128, NN - r * 128);   // + self-loops
}

// K2b: exclusive scan of rtot -> rbase (single small block).
__global__ __launch_bounds__(512) void rscan_kernel(const int* __restrict__ rtot,
                                                    int* __restrict__ rbase)
{
    __shared__ int wsum[8], wpre[8];
    const int tid = threadIdx.x, lane = tid & 63, wid = tid >> 6;
    int tot = (tid < NRANGE) ? rtot[tid] : 0;
    int incl = tot;
#pragma unroll
    for (int off = 1; off < 64; off <<= 1) {
        int t = __shfl_up(incl, off, 64);
        if (lane >= off) incl += t;
    }
    if (lane == 63) wsum[wid] = incl;
    __syncthreads();
    if (tid < 8) {
        int wv = wsum[tid], winc = wv;
#pragma unroll
        for (int off = 1; off < 8; off <<= 1) {
            int t = __shfl_up(winc, off, 64);
            if (tid >= off) winc += t;
        }
        wpre[tid] = winc - wv;
    }
    __syncthreads();
    const int excl = wpre[wid] + incl - tot;
    if (tid < NRANGE) rbase[tid] = excl;
    if (tid == NRANGE - 1) rbase[NRANGE] = excl + tot;
}

// ---------------------------------------------------------------------------
// K3: per-range gather + LDS counting sort -> offs + csrpack (src|dst<<16).
__global__ __launch_bounds__(256) void phaseB_kernel(
    const int* __restrict__ boffs,
    const unsigned int* __restrict__ blocksorted,
    const int* __restrict__ rbase,
    int* __restrict__ offs,
    unsigned int* __restrict__ csrpack)
{
    __shared__ unsigned int rec[RCAP];
    __shared__ unsigned int outpk[RCAP];
    __shared__ int runoff[NBLK + 1];
    __shared__ int bstart[NBLK];
    __shared__ int hist[128], lofs[128], cur[128];
    __shared__ int wsum4[4];
    __shared__ int tot0_s;

    const int r = blockIdx.x, tid = threadIdx.x;
    const int lane = tid & 63, wid = tid >> 6;
    const int base = r * 128;
    const int rn   = min(128, NN - base);

    int cnt = 0;
    if (tid < NBLK) {
        const int* bp = boffs + tid * (NRANGE + 1) + r;
        const int s = bp[0];
        bstart[tid] = s;
        cnt = bp[1] - s;
    }
    if (tid < 128) hist[tid] = 0;
    int incl = cnt;
#pragma unroll
    for (int off = 1; off < 64; off <<= 1) {
        int t = __shfl_up(incl, off, 64);
        if (lane >= off) incl += t;
    }
    if (lane == 63) wsum4[wid] = incl;
    __syncthreads();
    if (tid == 0) {
        int s = 0;
#pragma unroll
        for (int w = 0; w < 4; ++w) { int t = wsum4[w]; wsum4[w] = s; s += t; }
    }
    __syncthreads();
    const int excl = wsum4[wid] + incl - cnt;
    if (tid <= NBLK) runoff[tid] = excl;
    __syncthreads();

    const int tot8 = runoff[NBLK];
    for (int i = tid; i < tot8; i += 256) {
        int lo = 0, hi = NBLK;
        while (lo + 1 < hi) {
            const int mid = (lo + hi) >> 1;
            if (runoff[mid] <= i) lo = mid; else hi = mid;
        }
        rec[i] = blocksorted[(size_t)lo * EPB + bstart[lo] + (i - runoff[lo])];
    }
    for (int t = tid; t < rn; t += 256)                 // self-loops
        rec[tot8 + t] = (unsigned int)(base + t) | ((unsigned int)t << 16);
    const int total = min(tot8 + rn, RCAP);
    __syncthreads();

    for (int t = tid; t < total; t += 256) atomicAdd(&hist[rec[t] >> 16], 1);
    __syncthreads();

    if (tid < 64) {
        int v = hist[tid], incl2 = v;
#pragma unroll
        for (int off = 1; off < 64; off <<= 1) {
            int t = __shfl_up(incl2, off, 64);
            if (tid >= off) incl2 += t;
        }
        lofs[tid] = incl2 - v;
        if (tid == 63) tot0_s = incl2;
    }
    __syncthreads();
    if (tid >= 64 && tid < 128) {
        const int l = tid & 63;
        int v = hist[tid], incl2 = v;
#pragma unroll
        for (int off = 1; off < 64; off <<= 1) {
            int t = __shfl_up(incl2, off, 64);
            if (l >= off) incl2 += t;
        }
        lofs[tid] = tot0_s + incl2 - v;
    }
    __syncthreads();

    if (tid < 128) cur[tid] = lofs[tid];
    if (tid < rn) offs[base + tid] = rbase[r] + lofs[tid];
    if (r == 0 && tid == 0) offs[NN] = rbase[NRANGE];
    __syncthreads();

    for (int t = tid; t < total; t += 256) {
        const unsigned int rc = rec[t];
        const int pos = atomicAdd(&cur[rc >> 16], 1);
        outpk[pos] = (rc & 0xffffu) | ((unsigned int)(base + (rc >> 16)) << 16);
    }
    __syncthreads();
    const int rb = rbase[r];
    for (int t = tid; t < total; t += 256) csrpack[rb + t] = outpk[t];
}

// ---------------------------------------------------------------------------
// prep: per layer, ahat = W@a^T, pack W+ahat into pre-swizzled bf16 image.
__global__ __launch_bounds__(256) void prep_kernel(
    const float* __restrict__ W1, const float* __restrict__ a1s, const float* __restrict__ a1d,
    const float* __restrict__ W2, const float* __restrict__ a2s, const float* __restrict__ a2d,
    const float* __restrict__ W3, const float* __restrict__ a3s, const float* __restrict__ a3d,
    const float* __restrict__ W4, const float* __restrict__ a4s, const float* __restrict__ a4d,
    unsigned short* __restrict__ wtg)        // 4 * 144*128 bf16
{
    __shared__ float ahat_s[128 * 8];
    const int l = blockIdx.x, tid = threadIdx.x;
    const float *W, *as_, *ad_;
    int fo, nh;
    if (l == 0)      { W = W1; as_ = a1s; ad_ = a1d; fo = 128; nh = 4; }
    else if (l == 1) { W = W2; as_ = a2s; ad_ = a2d; fo = 128; nh = 4; }
    else if (l == 2) { W = W3; as_ = a3s; ad_ = a3d; fo = 128; nh = 4; }
    else             { W = W4; as_ = a4s; ad_ = a4d; fo = 32;  nh = 1; }
    const int F_STG = fo + 16;

    for (int item = tid; item < 128 * 8; item += 256) {
        const int k = item >> 3, j = item & 7;
        const int hh = j & 3;
        const bool is_d = j >= 4;
        float v = 0.f;
        if (hh < nh) {
            const float* av = (is_d ? ad_ : as_) + hh * 32;
            const float* wp = W + (size_t)k * fo + hh * 32;
#pragma unroll 8
            for (int c = 0; c < 32; ++c) v = fmaf(wp[c], av[c], v);
        }
        ahat_s[item] = v;
    }
    __syncthreads();

    unsigned short* outb = wtg + (size_t)l * (144 * 128);
    for (int p = tid; p < F_STG * 64; p += 256) {
        const int n  = p % F_STG;
        const int k2 = p / F_STG;
        float w0 = 0.f, w1 = 0.f;
        if (n < fo) {
            w0 = W[(size_t)(2 * k2) * fo + n];
            w1 = W[(size_t)(2 * k2 + 1) * fo + n];
        } else {
            const int j = n - fo;
            if (j < 8) {
                w0 = ahat_s[(2 * k2) * 8 + j];
                w1 = ahat_s[(2 * k2 + 1) * 8 + j];
            }
        }
        const unsigned int packed = f2bf2(w0, w1);
        const int byte = n * 256 + ((4 * k2) ^ ((n & 7) << 4));
        *reinterpret_cast<unsigned int*>(reinterpret_cast<char*>(outb) + byte) = packed;
    }
}

// ---------------------------------------------------------------------------
// hb = x @ W (bf16 MFMA).  128 rows/block (2 row-tiles reuse staged W image).
// XF32: read x as f32 and pack to bf16 in-register (layer 1).
template<int F_OUT, int NH, bool XF32>
__global__ __launch_bounds__(256) void gemm_mfma_kernel(
    const void* __restrict__ xv,
    const unsigned short* __restrict__ wtg,   // prepacked swizzled image
    unsigned short* __restrict__ hb,
    float* __restrict__ as_out, float* __restrict__ ad_out)
{
    constexpr int F_STG = F_OUT + 16;
    __shared__ unsigned short wt[F_STG * 128];
    const int tid = threadIdx.x;

    {
        const bf16x8* __restrict__ wg = reinterpret_cast<const bf16x8*>(wtg);
        bf16x8* wl = reinterpret_cast<bf16x8*>(wt);
        constexpr int NV = F_STG * 16;          // 16B vectors; NV % 256 == 0
#pragma unroll
        for (int i = 0; i < NV / 256; ++i)
            wl[i * 256 + tid] = wg[i * 256 + tid];
    }
    __syncthreads();

    const int wave = tid >> 6, lane = tid & 63;
    const int kchunk = (lane >> 4) * 8;
    const int kb_base = (lane >> 4) * 16;

#pragma unroll
    for (int rr = 0; rr < 2; ++rr) {
        const int row0 = blockIdx.x * 128 + rr * 64 + wave * 16;
        const int arow = row0 + (lane & 15);

        bf16x8 a[4];
        if (XF32) {
            if (arow < NN) {
                const float* __restrict__ ap = (const float*)xv + (size_t)arow * 128;
#pragma unroll
                for (int ks = 0; ks < 4; ++ks) {
                    const float4 f0 = *reinterpret_cast<const float4*>(ap + ks * 32 + kchunk);
                    const float4 f1 = *reinterpret_cast<const float4*>(ap + ks * 32 + kchunk + 4);
                    uint4 u;
                    u.x = f2bf2(f0.x, f0.y);
                    u.y = f2bf2(f0.z, f0.w);
                    u.z = f2bf2(f1.x, f1.y);
                    u.w = f2bf2(f1.z, f1.w);
                    bf16x8 v; __builtin_memcpy(&v, &u, 16);
                    a[ks] = v;
                }
            } else {
#pragma unroll
                for (int ks = 0; ks < 4; ++ks) a[ks] = bf16x8{0,0,0,0,0,0,0,0};
            }
        } else {
            const unsigned short* __restrict__ ap =
                (const unsigned short*)xv + (size_t)arow * 128;
#pragma unroll
            for (int ks = 0; ks < 4; ++ks)
                a[ks] = *reinterpret_cast<const bf16x8*>(ap + ks * 32 + kchunk);
        }

        const int rbase = row0 + (lane >> 4) * 4;

#pragma unroll
        for (int nt = 0; nt < F_OUT / 16; ++nt) {
            const int n = nt * 16 + (lane & 15);
            f32x4 acc = {0.f, 0.f, 0.f, 0.f};
#pragma unroll
            for (int ks = 0; ks < 4; ++ks) {
                const int byte = n * 256 + ((ks * 64 + kb_base) ^ ((n & 7) << 4));
                bf16x8 b = *reinterpret_cast<const bf16x8*>(
                    reinterpret_cast<const char*>(wt) + byte);
                acc = __builtin_amdgcn_mfma_f32_16x16x32_bf16(a[ks], b, acc, 0, 0, 0);
            }
#pragma unroll
            for (int r = 0; r < 4; ++r) {
                const int row = rbase + r;
                if (row < NN)
                    hb[(size_t)row * F_OUT + n] = f2bf(acc[r]);
            }
        }

        // ---- alpha tile ----
        {
            const int n = F_OUT + (lane & 15);
            f32x4 acc = {0.f, 0.f, 0.f, 0.f};
#pragma unroll
            for (int ks = 0; ks < 4; ++ks) {
                const int byte = n * 256 + ((ks * 64 + kb_base) ^ ((n & 7) << 4));
                bf16x8 b = *reinterpret_cast<const bf16x8*>(
                    reinterpret_cast<const char*>(wt) + byte);
                acc = __builtin_amdgcn_mfma_f32_16x16x32_bf16(a[ks], b, acc, 0, 0, 0);
            }
            const int col = lane & 15;
            if (col < 8) {
                const int hh = col & 3;
                const bool is_d = col >= 4;
                if (hh < NH) {
                    float* op = is_d ? ad_out : as_out;
#pragma unroll
                    for (int r = 0; r < 4; ++r) {
                        const int row = rbase + r;
                        if (row < NN) {
                            if (NH == 4) op[row * 4 + hh] = acc[r];
                            else         op[row]          = acc[r];
                        }
                    }
                }
            }
        }
    }
}

// ---------------------------------------------------------------------------
// Per-dst aggregation: 1 dst/wave, 4 waves/block, wave-synchronous.
// Deferred normalization; inline edge weights computed in the stage phase.
template<int HEADS, int F_OUT, bool OUT_BF16>
__global__ __launch_bounds__(256) void aggregate_kernel(
    const unsigned short* __restrict__ hlin,
    const float* __restrict__ as_,
    const float* __restrict__ ad_,
    const int* __restrict__ offs,
    const unsigned int* __restrict__ csrpack,
    const float* __restrict__ bias,
    void* __restrict__ out_v)
{
    __shared__ float w_all[4][64 * HEADS];
    __shared__ int   s_all[4][64];
    const int wave = threadIdx.x >> 6;
    const int lane = threadIdx.x & 63;
    const int d    = blockIdx.x * 4 + wave;
    if (d >= NN) return;
    float* __restrict__ w_lds   = w_all[wave];
    int*   __restrict__ src_lds = s_all[wave];

    const int beg = offs[d], end = offs[d + 1];

    float ad_h[HEADS];
#pragma unroll
    for (int h = 0; h < HEADS; ++h) ad_h[h] = ad_[d * HEADS + h];

    float acc[8] = {0.f, 0.f, 0.f, 0.f, 0.f, 0.f, 0.f, 0.f};
    float dsum = 0.f;
    const int q  = (F_OUT == 128) ? (lane >> 4) : (lane >> 2);   // edge sub-slot
    const int cl = (F_OUT == 128) ? (lane & 15) : (lane & 3);    // 8-ch group
    const int hd = (F_OUT == 128) ? (cl >> 2) : 0;               // head

    for (int base = beg; base < end; base += 64) {
        const int cnt = min(64, end - base);
        // ---- stage (src, ew) into per-wave LDS: one gather + HEADS exps ----
        {
            const int p = base + lane;
            const unsigned int pk = (p < end) ? csrpack[p] : 0u;
            const int src = (int)(pk & 0xffffu);
            src_lds[lane] = src;
            if (HEADS == 4) {
                float4 w4 = make_float4(0.f, 0.f, 0.f, 0.f);
                if (p < end) {
                    const float4 s4 = *reinterpret_cast<const float4*>(
                        as_ + (size_t)src * 4);
                    w4.x = __expf(leaky(s4.x + ad_h[0]));
                    w4.y = __expf(leaky(s4.y + ad_h[1]));
                    w4.z = __expf(leaky(s4.z + ad_h[2]));
                    w4.w = __expf(leaky(s4.w + ad_h[3]));
                }
                *reinterpret_cast<float4*>(w_lds + lane * 4) = w4;
            } else {
                float w1 = 0.f;
                if (p < end) w1 = __expf(leaky(as_[src] + ad_h[0]));
                w_lds[lane] = w1;
            }
        }
        asm volatile("s_waitcnt lgkmcnt(0)" ::: "memory");

        if (F_OUT == 128) {
            const int cntR = (cnt + 3) & ~3;
#pragma unroll 4
            for (int j = 0; j < cntR; j += 4) {
                const int   slot = j + q;
                const int   srcj = src_lds[slot];
                const float w    = w_lds[slot * 4 + hd];
                const uint4 hv   = *reinterpret_cast<const uint4*>(
                    hlin + (size_t)srcj * 128 + cl * 8);
                dsum += w;
                acc[0] = fmaf(w, bflo(hv.x), acc[0]);
                acc[1] = fmaf(w, bfhi(hv.x), acc[1]);
                acc[2] = fmaf(w, bflo(hv.y), acc[2]);
                acc[3] = fmaf(w, bfhi(hv.y), acc[3]);
                acc[4] = fmaf(w, bflo(hv.z), acc[4]);
                acc[5] = fmaf(w, bfhi(hv.z), acc[5]);
                acc[6] = fmaf(w, bflo(hv.w), acc[6]);
                acc[7] = fmaf(w, bfhi(hv.w), acc[7]);
            }
        } else {
            const int cntR = (cnt + 15) & ~15;
#pragma unroll 4
            for (int j = 0; j < cntR; j += 16) {
                const int   slot = j + q;
                const int   srcj = src_lds[slot];
                const float w    = w_lds[slot];
                const uint4 hv   = *reinterpret_cast<const uint4*>(
                    hlin + (size_t)srcj * 32 + cl * 8);
                dsum += w;
                acc[0] = fmaf(w, bflo(hv.x), acc[0]);
                acc[1] = fmaf(w, bfhi(hv.x), acc[1]);
                acc[2] = fmaf(w, bflo(hv.y), acc[2]);
                acc[3] = fmaf(w, bfhi(hv.y), acc[3]);
                acc[4] = fmaf(w, bflo(hv.z), acc[4]);
                acc[5] = fmaf(w, bfhi(hv.z), acc[5]);
                acc[6] = fmaf(w, bflo(hv.w), acc[6]);
                acc[7] = fmaf(w, bfhi(hv.w), acc[7]);
            }
        }
        // LDS reuse across chunks is safe: wave-synchronous (each lane's next
        // ds_write happens after its own ds_reads of the previous chunk).
    }

    if (F_OUT == 128) {
#pragma unroll
        for (int t = 0; t < 8; ++t) {
            acc[t] += __shfl_xor(acc[t], 16, 64);
            acc[t] += __shfl_xor(acc[t], 32, 64);
        }
        dsum += __shfl_xor(dsum, 16, 64);
        dsum += __shfl_xor(dsum, 32, 64);
        if (lane < 16) {
            const float rinv = 1.f / (dsum + 1e-16f);
            const int c0 = lane * 8;
            float v[8];
#pragma unroll
            for (int t = 0; t < 8; ++t) v[t] = elu(fmaf(acc[t], rinv, bias[c0 + t]));
            uint4 pk;
            pk.x = f2bf2(v[0], v[1]);
            pk.y = f2bf2(v[2], v[3]);
            pk.z = f2bf2(v[4], v[5]);
            pk.w = f2bf2(v[6], v[7]);
            *reinterpret_cast<uint4*>((unsigned short*)out_v + (size_t)d * 128 + c0) = pk;
        }
    } else {
#pragma unroll
        for (int t = 0; t < 8; ++t) {
            acc[t] += __shfl_xor(acc[t], 4, 64);
            acc[t] += __shfl_xor(acc[t], 8, 64);
            acc[t] += __shfl_xor(acc[t], 16, 64);
            acc[t] += __shfl_xor(acc[t], 32, 64);
        }
        dsum += __shfl_xor(dsum, 4, 64);
        dsum += __shfl_xor(dsum, 8, 64);
        dsum += __shfl_xor(dsum, 16, 64);
        dsum += __shfl_xor(dsum, 32, 64);
        if (lane < 4) {
            const float rinv = 1.f / (dsum + 1e-16f);
            const int c0 = lane * 8;
            float v[8];
#pragma unroll
            for (int t = 0; t < 8; ++t) v[t] = elu(fmaf(acc[t], rinv, bias[c0 + t]));
            float* op = (float*)out_v + (size_t)d * 32 + c0;
            *reinterpret_cast<float4*>(op)     = make_float4(v[0], v[1], v[2], v[3]);
            *reinterpret_cast<float4*>(op + 4) = make_float4(v[4], v[5], v[6], v[7]);
        }
    }
}

// ---------------------------------------------------------------------------
__global__ __launch_bounds__(256) void pool_fc_kernel(
    const float* __restrict__ h4, const int* __restrict__ batch,
    const float* __restrict__ fcW, const float* __restrict__ fcb,
    float* __restrict__ out)
{
    const int g = blockIdx.x;
    __shared__ int sb, se;
    if (threadIdx.x == 0) {
        int lo = 0, hi = NN;
        while (lo < hi) { int mid = (lo + hi) >> 1; if (batch[mid] < g) lo = mid + 1; else hi = mid; }
        sb = lo;
        lo = sb; hi = NN;
        while (lo < hi) { int mid = (lo + hi) >> 1; if (batch[mid] < g + 1) lo = mid + 1; else hi = mid; }
        se = lo;
    }
    __syncthreads();
    const int s = sb, e = se;

    const int c  = threadIdx.x & 31;
    const int rg = threadIdx.x >> 5;
    float acc = 0.f;
    for (int n = s + rg; n < e; n += 8)
        acc += h4[(size_t)n * HIDC + c];

    __shared__ float red[8][32];
    red[rg][c] = acc;
    __syncthreads();
    __shared__ float pooled_s[32];
    if (threadIdx.x < 32) {
        float v = 0.f;
#pragma unroll
        for (int r = 0; r < 8; ++r) v += red[r][threadIdx.x];
        pooled_s[threadIdx.x] = v / fmaxf((float)(e - s), 1.f);
    }
    __syncthreads();
    if (threadIdx.x < OUTC) {
        const int o = threadIdx.x;
        float a2 = fcb[o];
#pragma unroll
        for (int cc = 0; cc < HIDC; ++cc)
            a2 = fmaf(pooled_s[cc], fcW[cc * OUTC + o], a2);
        out[g * OUTC + o] = a2;
    }
}

// ---------------------------------------------------------------------------
extern "C" void kernel_launch(void* const* d_in, const int* in_sizes, int n_in,
                              void* d_out, int out_size, void* d_ws, size_t ws_size,
                              hipStream_t stream)
{
    const float* x     = (const float*)d_in[0];
    const int*   ei    = (const int*)d_in[1];
    const int*   batch = (const int*)d_in[2];
    const float* W1  = (const float*)d_in[3];
    const float* a1s = (const float*)d_in[4];
    const float* a1d = (const float*)d_in[5];
    const float* b1  = (const float*)d_in[6];
    const float* W2  = (const float*)d_in[7];
    const float* a2s = (const float*)d_in[8];
    const float* a2d = (const float*)d_in[9];
    const float* b2  = (const float*)d_in[10];
    const float* W3  = (const float*)d_in[11];
    const float* a3s = (const float*)d_in[12];
    const float* a3d = (const float*)d_in[13];
    const float* b3  = (const float*)d_in[14];
    const float* W4  = (const float*)d_in[15];
    const float* a4s = (const float*)d_in[16];
    const float* a4d = (const float*)d_in[17];
    const float* b4  = (const float*)d_in[18];
    const float* fcW = (const float*)d_in[19];
    const float* fcb = (const float*)d_in[20];
    float* out = (float*)d_out;

    // workspace layout (overlays: blocksorted aliases hb; bufF aliases xb)
    unsigned short* xb = (unsigned short*)d_ws;                 // NNPAD*128 bf16
    unsigned short* hb = xb + (size_t)NNPAD * 128;              // NNPAD*128 bf16
    float* asb  = (float*)(hb + (size_t)NNPAD * 128);           // N*4
    float* adb  = asb + (size_t)NN * 4;                         // N*4
    int*   offs    = (int*)(adb + (size_t)NN * 4);              // N+1
    unsigned int* csrpack = (unsigned int*)(offs + NN + 1);     // E+N (src|dst<<16)
    int*   boffs  = (int*)(csrpack + ETOT);                     // NBLK*(NRANGE+1)
    int*   rbase  = boffs + NBLK * (NRANGE + 1);                // NRANGE+1
    int*   rtot   = rbase + NRANGE + 1;                         // NRANGE
    unsigned short* wtg = (unsigned short*)(rtot + NRANGE);     // 4*144*128 bf16
    unsigned int* blocksorted = (unsigned int*)hb;              // NBLK*EPB (alias)
    float* bufF = (float*)xb;                                   // N*32 f32 (alias)

    // ---- CSR build ----
    local_sort_kernel<<<NBLK, 256, 0, stream>>>(ei, blocksorted, boffs);
    rtot_kernel<<<(NRANGE + 3) / 4, 256, 0, stream>>>(boffs, rtot);
    rscan_kernel<<<1, 512, 0, stream>>>(rtot, rbase);
    phaseB_kernel<<<NRANGE, 256, 0, stream>>>(boffs, blocksorted, rbase, offs, csrpack);

    // ---- prep (W+ahat -> prepacked bf16 swizzled images) ----
    prep_kernel<<<4, 256, 0, stream>>>(W1, a1s, a1d, W2, a2s, a2d,
                                       W3, a3s, a3d, W4, a4s, a4d, wtg);

    constexpr int GEMM_GRID = NNPAD / 128;      // 391
    constexpr int AGG_GRID  = (NN + 3) / 4;     // 12500
    constexpr size_t WSTRIDE = 144 * 128;

    // ---- layer 1 (reads x f32 directly) ----
    gemm_mfma_kernel<128, 4, true><<<GEMM_GRID, 256, 0, stream>>>(x, wtg + 0 * WSTRIDE, hb, asb, adb);
    aggregate_kernel<4, 128, true><<<AGG_GRID, 256, 0, stream>>>(hb, asb, adb, offs, csrpack, b1, xb);
    // ---- layer 2 ----
    gemm_mfma_kernel<128, 4, false><<<GEMM_GRID, 256, 0, stream>>>(xb, wtg + 1 * WSTRIDE, hb, asb, adb);
    aggregate_kernel<4, 128, true><<<AGG_GRID, 256, 0, stream>>>(hb, asb, adb, offs, csrpack, b2, xb);
    // ---- layer 3 ----
    gemm_mfma_kernel<128, 4, false><<<GEMM_GRID, 256, 0, stream>>>(xb, wtg + 2 * WSTRIDE, hb, asb, adb);
    aggregate_kernel<4, 128, true><<<AGG_GRID, 256, 0, stream>>>(hb, asb, adb, offs, csrpack, b3, xb);
    // ---- layer 4 (heads=1, 32 ch, f32 out) ----
    gemm_mfma_kernel<32, 1, false><<<GEMM_GRID, 256, 0, stream>>>(xb, wtg + 3 * WSTRIDE, hb, asb, adb);
    aggregate_kernel<1, 32, false><<<AGG_GRID, 256, 0, stream>>>(hb, asb, adb, offs, csrpack, b4, bufF);

    // ---- fused mean pool + FC ----
    pool_fc_kernel<<<GG, 256, 0, stream>>>(bufF, batch, fcW, fcb, out);
}

// Round 13
// 240.407 us; speedup vs baseline: 1.1807x; 1.0736x over previous
//
#include <hip/hip_runtime.h>
#include <hip/hip_bf16.h>

// ---------------------------------------------------------------------------
// GAT (4-layer) on MI355X, bf16 datapath with f32 accumulation.
//   CSR build (zero global atomics, coalesced writes):
//     local_sort (fused with gemm1) -> rtot + rscan -> phaseB counting sort.
//     csrpack[p] = src | dst<<16.
//   prep_kernel: per layer, pack W + ahat=W@a^T into pre-swizzled bf16 image.
//   Per layer:
//     gemm_mfma  (128 rows/block; bf16 MFMA 16x16x32; alpha via extra tile)
//     aggregate  (1 dst/wave, 4 waves/block; wave-synchronous; deferred
//                 normalization: stage computes ew=exp(leaky(as[src]+ad[d]))
//                 inline into per-wave LDS; inner acc += ew*h, dsum += ew;
//                 epilogue out = elu(acc/dsum + bias); uint4 gathers 8ch/lane)
//   gemm1 is co-launched with local_sort (independent work, fills idle CUs).
//   Final: fused pool+FC (batch sorted -> contiguous ranges).
// ---------------------------------------------------------------------------

constexpr int NN     = 50000;
constexpr int NNPAD  = 50048;
constexpr int EE     = 800000;
constexpr int ETOT   = EE + NN;
constexpr int GG     = 128;
constexpr int HIDC   = 32;
constexpr int OUTC   = 64;

constexpr int NRANGE = (NN + 127) / 128;   // 391 dst ranges
constexpr int EPB    = 4096;               // edges per local_sort block
constexpr int NBLK   = (EE + EPB - 1) / EPB;  // 196
constexpr int RCAP   = 2688;               // per-range record capacity

typedef short  bf16x8 __attribute__((ext_vector_type(8)));
typedef float  f32x4  __attribute__((ext_vector_type(4)));

static __device__ __forceinline__ unsigned short f2bf(float f) {
    __hip_bfloat16 h = __float2bfloat16(f);
    unsigned short u; __builtin_memcpy(&u, &h, 2); return u;
}
static __device__ __forceinline__ unsigned int f2bf2(float lo, float hi) {
    __hip_bfloat162 h2 = __float22bfloat162_rn(make_float2(lo, hi));
    unsigned int u; __builtin_memcpy(&u, &h2, 4); return u;
}
static __device__ __forceinline__ float bflo(unsigned int v) {
    return __uint_as_float(v << 16);
}
static __device__ __forceinline__ float bfhi(unsigned int v) {
    return __uint_as_float(v & 0xffff0000u);
}
static __device__ __forceinline__ float elu(float v) {
    return (v > 0.f) ? v : (__expf(v) - 1.f);
}
static __device__ __forceinline__ float leaky(float e) {
    return fmaxf(e, 0.f) + 0.2f * fminf(e, 0.f);
}

// ---------------------------------------------------------------------------
// local_sort body: per-block LDS sort of 4096 edges by dst-range.
// smem layout: sorted[EPB] u32 | hist[392] | scanv[392] | cur[392] | wsum4[4] | ct[1]
static __device__ void local_sort_body(
    char* smem, const int* __restrict__ ei,
    unsigned int* __restrict__ blocksorted, int* __restrict__ boffs, int b)
{
    unsigned int* sorted = reinterpret_cast<unsigned int*>(smem);
    int* hist  = reinterpret_cast<int*>(smem + EPB * 4);
    int* scanv = hist + (NRANGE + 1);
    int* cur   = scanv + (NRANGE + 1);
    int* wsum4 = cur + (NRANGE + 1);
    int* ct_s  = wsum4 + 4;

    const int tid = threadIdx.x;
    const int lane = tid & 63, wid = tid >> 6;
    const int e0 = b * EPB;
    const int ecnt = min(EPB, EE - e0);

    for (int t = tid; t < NRANGE + 1; t += 256) hist[t] = 0;
    __syncthreads();

    unsigned int recs[16];
    int rkey[16];
#pragma unroll
    for (int k = 0; k < 16; ++k) {
        const int idx = tid + k * 256;
        rkey[k] = -1;
        if (idx < ecnt) {
            const int src = ei[e0 + idx];
            const int dst = ei[EE + e0 + idx];
            const int r = dst >> 7;
            recs[k] = (unsigned int)src | ((unsigned int)(dst & 127) << 16);
            rkey[k] = r;
            atomicAdd(&hist[r], 1);
        }
    }
    __syncthreads();

    int carry = 0;
    for (int base = 0; base < NRANGE + 1; base += 256) {
        const int i = base + tid;
        const int v = (i < NRANGE + 1) ? hist[i] : 0;
        int incl = v;
#pragma unroll
        for (int off = 1; off < 64; off <<= 1) {
            int t = __shfl_up(incl, off, 64);
            if (lane >= off) incl += t;
        }
        if (lane == 63) wsum4[wid] = incl;
        __syncthreads();
        if (tid == 0) {
            int s = 0;
#pragma unroll
            for (int w = 0; w < 4; ++w) { int t = wsum4[w]; wsum4[w] = s; s += t; }
            *ct_s = s;
        }
        __syncthreads();
        const int excl = carry + wsum4[wid] + incl - v;
        if (i < NRANGE + 1) { scanv[i] = excl; cur[i] = excl; }
        carry += *ct_s;
        __syncthreads();
    }

#pragma unroll
    for (int k = 0; k < 16; ++k) {
        if (rkey[k] >= 0) {
            const int pos = atomicAdd(&cur[rkey[k]], 1);
            sorted[pos] = recs[k];
        }
    }
    __syncthreads();

    for (int t = tid; t < ecnt; t += 256)
        blocksorted[(size_t)b * EPB + t] = sorted[t];
    for (int t = tid; t < NRANGE + 1; t += 256)
        boffs[b * (NRANGE + 1) + t] = scanv[t];
}

// ---------------------------------------------------------------------------
// gemm body: hb = x @ W (bf16 MFMA), 128 rows/block, alpha via extra tile.
// smem: wt[F_STG*128] bf16 (prepacked swizzled image copied with 16B vectors)
template<int F_OUT, int NH, bool XF32>
static __device__ void gemm_body(
    char* smem, const void* __restrict__ xv,
    const unsigned short* __restrict__ wtg,
    unsigned short* __restrict__ hb,
    float* __restrict__ as_out, float* __restrict__ ad_out, int bid)
{
    constexpr int F_STG = F_OUT + 16;
    unsigned short* wt = reinterpret_cast<unsigned short*>(smem);
    const int tid = threadIdx.x;

    {
        const bf16x8* __restrict__ wg = reinterpret_cast<const bf16x8*>(wtg);
        bf16x8* wl = reinterpret_cast<bf16x8*>(wt);
        constexpr int NV = F_STG * 16;          // 16B vectors; NV % 256 == 0
#pragma unroll
        for (int i = 0; i < NV / 256; ++i)
            wl[i * 256 + tid] = wg[i * 256 + tid];
    }
    __syncthreads();

    const int wave = tid >> 6, lane = tid & 63;
    const int kchunk = (lane >> 4) * 8;
    const int kb_base = (lane >> 4) * 16;

#pragma unroll
    for (int rr = 0; rr < 2; ++rr) {
        const int row0 = bid * 128 + rr * 64 + wave * 16;
        const int arow = row0 + (lane & 15);

        bf16x8 a[4];
        if (XF32) {
            if (arow < NN) {
                const float* __restrict__ ap = (const float*)xv + (size_t)arow * 128;
#pragma unroll
                for (int ks = 0; ks < 4; ++ks) {
                    const float4 f0 = *reinterpret_cast<const float4*>(ap + ks * 32 + kchunk);
                    const float4 f1 = *reinterpret_cast<const float4*>(ap + ks * 32 + kchunk + 4);
                    uint4 u;
                    u.x = f2bf2(f0.x, f0.y);
                    u.y = f2bf2(f0.z, f0.w);
                    u.z = f2bf2(f1.x, f1.y);
                    u.w = f2bf2(f1.z, f1.w);
                    bf16x8 v; __builtin_memcpy(&v, &u, 16);
                    a[ks] = v;
                }
            } else {
#pragma unroll
                for (int ks = 0; ks < 4; ++ks) a[ks] = bf16x8{0,0,0,0,0,0,0,0};
            }
        } else {
            const unsigned short* __restrict__ ap =
                (const unsigned short*)xv + (size_t)arow * 128;
#pragma unroll
            for (int ks = 0; ks < 4; ++ks)
                a[ks] = *reinterpret_cast<const bf16x8*>(ap + ks * 32 + kchunk);
        }

        const int rbase = row0 + (lane >> 4) * 4;

#pragma unroll
        for (int nt = 0; nt < F_OUT / 16; ++nt) {
            const int n = nt * 16 + (lane & 15);
            f32x4 acc = {0.f, 0.f, 0.f, 0.f};
#pragma unroll
            for (int ks = 0; ks < 4; ++ks) {
                const int byte = n * 256 + ((ks * 64 + kb_base) ^ ((n & 7) << 4));
                bf16x8 b = *reinterpret_cast<const bf16x8*>(
                    reinterpret_cast<const char*>(wt) + byte);
                acc = __builtin_amdgcn_mfma_f32_16x16x32_bf16(a[ks], b, acc, 0, 0, 0);
            }
#pragma unroll
            for (int r = 0; r < 4; ++r) {
                const int row = rbase + r;
                if (row < NN)
                    hb[(size_t)row * F_OUT + n] = f2bf(acc[r]);
            }
        }

        // ---- alpha tile ----
        {
            const int n = F_OUT + (lane & 15);
            f32x4 acc = {0.f, 0.f, 0.f, 0.f};
#pragma unroll
            for (int ks = 0; ks < 4; ++ks) {
                const int byte = n * 256 + ((ks * 64 + kb_base) ^ ((n & 7) << 4));
                bf16x8 b = *reinterpret_cast<const bf16x8*>(
                    reinterpret_cast<const char*>(wt) + byte);
                acc = __builtin_amdgcn_mfma_f32_16x16x32_bf16(a[ks], b, acc, 0, 0, 0);
            }
            const int col = lane & 15;
            if (col < 8) {
                const int hh = col & 3;
                const bool is_d = col >= 4;
                if (hh < NH) {
                    float* op = is_d ? ad_out : as_out;
#pragma unroll
                    for (int r = 0; r < 4; ++r) {
                        const int row = rbase + r;
                        if (row < NN) {
                            if (NH == 4) op[row * 4 + hh] = acc[r];
                            else         op[row]          = acc[r];
                        }
                    }
                }
            }
        }
    }
}

// ---------------------------------------------------------------------------
// Fused launch: blocks [0,NBLK) run local_sort; [NBLK, NBLK+391) run gemm1.
// Independent work (sort needs only edge_index; gemm1 needs only x + wtg).
constexpr int FUSED_SMEM = 144 * 128 * 2;   // gemm wt (36864 B) > sort (~21 KB)

__global__ __launch_bounds__(256) void fused_ls_gemm1_kernel(
    const int* __restrict__ ei,
    unsigned int* __restrict__ blocksorted,
    int* __restrict__ boffs,
    const float* __restrict__ x,
    const unsigned short* __restrict__ wtg,
    unsigned short* __restrict__ hb,
    float* __restrict__ as_out, float* __restrict__ ad_out)
{
    __shared__ char smem[FUSED_SMEM];
    if (blockIdx.x < NBLK)
        local_sort_body(smem, ei, blocksorted, boffs, blockIdx.x);
    else
        gemm_body<128, 4, true>(smem, x, wtg, hb, as_out, ad_out,
                                blockIdx.x - NBLK);
}

// Standalone gemm kernel (layers 2-4).
template<int F_OUT, int NH>
__global__ __launch_bounds__(256) void gemm_mfma_kernel(
    const void* __restrict__ xv,
    const unsigned short* __restrict__ wtg,
    unsigned short* __restrict__ hb,
    float* __restrict__ as_out, float* __restrict__ ad_out)
{
    __shared__ char smem[(F_OUT + 16) * 128 * 2];
    gemm_body<F_OUT, NH, false>(smem, xv, wtg, hb, as_out, ad_out, blockIdx.x);
}

// ---------------------------------------------------------------------------
// K2a: per-range totals (parallel over ranges; one wave per range).
__global__ __launch_bounds__(256) void rtot_kernel(const int* __restrict__ boffs,
                                                   int* __restrict__ rtot)
{
    const int r = blockIdx.x * 4 + (threadIdx.x >> 6);
    const int lane = threadIdx.x & 63;
    if (r >= NRANGE) return;
    int tot = 0;
    for (int b = lane; b < NBLK; b += 64) {
        const int* bp = boffs + b * (NRANGE + 1) + r;
        tot += bp[1] - bp[0];
    }
#pragma unroll
    for (int k = 1; k < 64; k <<= 1) tot += __shfl_xor(tot, k, 64);
    if (lane == 0) rtot[r] = tot + min(128, NN - r * 128);   // + self-loops
}

// K2b: exclusive scan of rtot -> rbase (single small block).
__global__ __launch_bounds__(512) void rscan_kernel(const int* __restrict__ rtot,
                                                    int* __restrict__ rbase)
{
    __shared__ int wsum[8], wpre[8];
    const int tid = threadIdx.x, lane = tid & 63, wid = tid >> 6;
    int tot = (tid < NRANGE) ? rtot[tid] : 0;
    int incl = tot;
#pragma unroll
    for (int off = 1; off < 64; off <<= 1) {
        int t = __shfl_up(incl, off, 64);
        if (lane >= off) incl += t;
    }
    if (lane == 63) wsum[wid] = incl;
    __syncthreads();
    if (tid < 8) {
        int wv = wsum[tid], winc = wv;
#pragma unroll
        for (int off = 1; off < 8; off <<= 1) {
            int t = __shfl_up(winc, off, 64);
            if (tid >= off) winc += t;
        }
        wpre[tid] = winc - wv;
    }
    __syncthreads();
    const int excl = wpre[wid] + incl - tot;
    if (tid < NRANGE) rbase[tid] = excl;
    if (tid == NRANGE - 1) rbase[NRANGE] = excl + tot;
}

// ---------------------------------------------------------------------------
// K3: per-range gather + LDS counting sort -> offs + csrpack (src|dst<<16).
__global__ __launch_bounds__(256) void phaseB_kernel(
    const int* __restrict__ boffs,
    const unsigned int* __restrict__ blocksorted,
    const int* __restrict__ rbase,
    int* __restrict__ offs,
    unsigned int* __restrict__ csrpack)
{
    __shared__ unsigned int rec[RCAP];
    __shared__ unsigned int outpk[RCAP];
    __shared__ int runoff[NBLK + 1];
    __shared__ int bstart[NBLK];
    __shared__ int hist[128], lofs[128], cur[128];
    __shared__ int wsum4[4];
    __shared__ int tot0_s;

    const int r = blockIdx.x, tid = threadIdx.x;
    const int lane = tid & 63, wid = tid >> 6;
    const int base = r * 128;
    const int rn   = min(128, NN - base);

    int cnt = 0;
    if (tid < NBLK) {
        const int* bp = boffs + tid * (NRANGE + 1) + r;
        const int s = bp[0];
        bstart[tid] = s;
        cnt = bp[1] - s;
    }
    if (tid < 128) hist[tid] = 0;
    int incl = cnt;
#pragma unroll
    for (int off = 1; off < 64; off <<= 1) {
        int t = __shfl_up(incl, off, 64);
        if (lane >= off) incl += t;
    }
    if (lane == 63) wsum4[wid] = incl;
    __syncthreads();
    if (tid == 0) {
        int s = 0;
#pragma unroll
        for (int w = 0; w < 4; ++w) { int t = wsum4[w]; wsum4[w] = s; s += t; }
    }
    __syncthreads();
    const int excl = wsum4[wid] + incl - cnt;
    if (tid <= NBLK) runoff[tid] = excl;
    __syncthreads();

    const int tot8 = runoff[NBLK];
    for (int i = tid; i < tot8; i += 256) {
        int lo = 0, hi = NBLK;
        while (lo + 1 < hi) {
            const int mid = (lo + hi) >> 1;
            if (runoff[mid] <= i) lo = mid; else hi = mid;
        }
        rec[i] = blocksorted[(size_t)lo * EPB + bstart[lo] + (i - runoff[lo])];
    }
    for (int t = tid; t < rn; t += 256)                 // self-loops
        rec[tot8 + t] = (unsigned int)(base + t) | ((unsigned int)t << 16);
    const int total = min(tot8 + rn, RCAP);
    __syncthreads();

    for (int t = tid; t < total; t += 256) atomicAdd(&hist[rec[t] >> 16], 1);
    __syncthreads();

    if (tid < 64) {
        int v = hist[tid], incl2 = v;
#pragma unroll
        for (int off = 1; off < 64; off <<= 1) {
            int t = __shfl_up(incl2, off, 64);
            if (tid >= off) incl2 += t;
        }
        lofs[tid] = incl2 - v;
        if (tid == 63) tot0_s = incl2;
    }
    __syncthreads();
    if (tid >= 64 && tid < 128) {
        const int l = tid & 63;
        int v = hist[tid], incl2 = v;
#pragma unroll
        for (int off = 1; off < 64; off <<= 1) {
            int t = __shfl_up(incl2, off, 64);
            if (l >= off) incl2 += t;
        }
        lofs[tid] = tot0_s + incl2 - v;
    }
    __syncthreads();

    if (tid < 128) cur[tid] = lofs[tid];
    if (tid < rn) offs[base + tid] = rbase[r] + lofs[tid];
    if (r == 0 && tid == 0) offs[NN] = rbase[NRANGE];
    __syncthreads();

    for (int t = tid; t < total; t += 256) {
        const unsigned int rc = rec[t];
        const int pos = atomicAdd(&cur[rc >> 16], 1);
        outpk[pos] = (rc & 0xffffu) | ((unsigned int)(base + (rc >> 16)) << 16);
    }
    __syncthreads();
    const int rb = rbase[r];
    for (int t = tid; t < total; t += 256) csrpack[rb + t] = outpk[t];
}

// ---------------------------------------------------------------------------
// prep: per layer, ahat = W@a^T, pack W+ahat into pre-swizzled bf16 image.
__global__ __launch_bounds__(256) void prep_kernel(
    const float* __restrict__ W1, const float* __restrict__ a1s, const float* __restrict__ a1d,
    const float* __restrict__ W2, const float* __restrict__ a2s, const float* __restrict__ a2d,
    const float* __restrict__ W3, const float* __restrict__ a3s, const float* __restrict__ a3d,
    const float* __restrict__ W4, const float* __restrict__ a4s, const float* __restrict__ a4d,
    unsigned short* __restrict__ wtg)        // 4 * 144*128 bf16
{
    __shared__ float ahat_s[128 * 8];
    const int l = blockIdx.x, tid = threadIdx.x;
    const float *W, *as_, *ad_;
    int fo, nh;
    if (l == 0)      { W = W1; as_ = a1s; ad_ = a1d; fo = 128; nh = 4; }
    else if (l == 1) { W = W2; as_ = a2s; ad_ = a2d; fo = 128; nh = 4; }
    else if (l == 2) { W = W3; as_ = a3s; ad_ = a3d; fo = 128; nh = 4; }
    else             { W = W4; as_ = a4s; ad_ = a4d; fo = 32;  nh = 1; }
    const int F_STG = fo + 16;

    for (int item = tid; item < 128 * 8; item += 256) {
        const int k = item >> 3, j = item & 7;
        const int hh = j & 3;
        const bool is_d = j >= 4;
        float v = 0.f;
        if (hh < nh) {
            const float* av = (is_d ? ad_ : as_) + hh * 32;
            const float* wp = W + (size_t)k * fo + hh * 32;
#pragma unroll 8
            for (int c = 0; c < 32; ++c) v = fmaf(wp[c], av[c], v);
        }
        ahat_s[item] = v;
    }
    __syncthreads();

    unsigned short* outb = wtg + (size_t)l * (144 * 128);
    for (int p = tid; p < F_STG * 64; p += 256) {
        const int n  = p % F_STG;
        const int k2 = p / F_STG;
        float w0 = 0.f, w1 = 0.f;
        if (n < fo) {
            w0 = W[(size_t)(2 * k2) * fo + n];
            w1 = W[(size_t)(2 * k2 + 1) * fo + n];
        } else {
            const int j = n - fo;
            if (j < 8) {
                w0 = ahat_s[(2 * k2) * 8 + j];
                w1 = ahat_s[(2 * k2 + 1) * 8 + j];
            }
        }
        const unsigned int packed = f2bf2(w0, w1);
        const int byte = n * 256 + ((4 * k2) ^ ((n & 7) << 4));
        *reinterpret_cast<unsigned int*>(reinterpret_cast<char*>(outb) + byte) = packed;
    }
}

// ---------------------------------------------------------------------------
// Per-dst aggregation: 1 dst/wave, 4 waves/block, wave-synchronous.
// Deferred normalization; inline edge weights computed in the stage phase.
template<int HEADS, int F_OUT, bool OUT_BF16>
__global__ __launch_bounds__(256) void aggregate_kernel(
    const unsigned short* __restrict__ hlin,
    const float* __restrict__ as_,
    const float* __restrict__ ad_,
    const int* __restrict__ offs,
    const unsigned int* __restrict__ csrpack,
    const float* __restrict__ bias,
    void* __restrict__ out_v)
{
    __shared__ float w_all[4][64 * HEADS];
    __shared__ int   s_all[4][64];
    const int wave = threadIdx.x >> 6;
    const int lane = threadIdx.x & 63;
    const int d    = blockIdx.x * 4 + wave;
    if (d >= NN) return;
    float* __restrict__ w_lds   = w_all[wave];
    int*   __restrict__ src_lds = s_all[wave];

    const int beg = offs[d], end = offs[d + 1];

    float ad_h[HEADS];
#pragma unroll
    for (int h = 0; h < HEADS; ++h) ad_h[h] = ad_[d * HEADS + h];

    float acc[8] = {0.f, 0.f, 0.f, 0.f, 0.f, 0.f, 0.f, 0.f};
    float dsum = 0.f;
    const int q  = (F_OUT == 128) ? (lane >> 4) : (lane >> 2);   // edge sub-slot
    const int cl = (F_OUT == 128) ? (lane & 15) : (lane & 3);    // 8-ch group
    const int hd = (F_OUT == 128) ? (cl >> 2) : 0;               // head

    for (int base = beg; base < end; base += 64) {
        const int cnt = min(64, end - base);
        // ---- stage (src, ew) into per-wave LDS: one gather + HEADS exps ----
        {
            const int p = base + lane;
            const unsigned int pk = (p < end) ? csrpack[p] : 0u;
            const int src = (int)(pk & 0xffffu);
            src_lds[lane] = src;
            if (HEADS == 4) {
                float4 w4 = make_float4(0.f, 0.f, 0.f, 0.f);
                if (p < end) {
                    const float4 s4 = *reinterpret_cast<const float4*>(
                        as_ + (size_t)src * 4);
                    w4.x = __expf(leaky(s4.x + ad_h[0]));
                    w4.y = __expf(leaky(s4.y + ad_h[1]));
                    w4.z = __expf(leaky(s4.z + ad_h[2]));
                    w4.w = __expf(leaky(s4.w + ad_h[3]));
                }
                *reinterpret_cast<float4*>(w_lds + lane * 4) = w4;
            } else {
                float w1 = 0.f;
                if (p < end) w1 = __expf(leaky(as_[src] + ad_h[0]));
                w_lds[lane] = w1;
            }
        }
        asm volatile("s_waitcnt lgkmcnt(0)" ::: "memory");

        if (F_OUT == 128) {
            const int cntR = (cnt + 3) & ~3;
#pragma unroll 2
            for (int j = 0; j < cntR; j += 4) {
                const int   slot = j + q;
                const int   srcj = src_lds[slot];
                const float w    = w_lds[slot * 4 + hd];
                const uint4 hv   = *reinterpret_cast<const uint4*>(
                    hlin + (size_t)srcj * 128 + cl * 8);
                dsum += w;
                acc[0] = fmaf(w, bflo(hv.x), acc[0]);
                acc[1] = fmaf(w, bfhi(hv.x), acc[1]);
                acc[2] = fmaf(w, bflo(hv.y), acc[2]);
                acc[3] = fmaf(w, bfhi(hv.y), acc[3]);
                acc[4] = fmaf(w, bflo(hv.z), acc[4]);
                acc[5] = fmaf(w, bfhi(hv.z), acc[5]);
                acc[6] = fmaf(w, bflo(hv.w), acc[6]);
                acc[7] = fmaf(w, bfhi(hv.w), acc[7]);
            }
        } else {
            const int cntR = (cnt + 15) & ~15;
#pragma unroll 2
            for (int j = 0; j < cntR; j += 16) {
                const int   slot = j + q;
                const int   srcj = src_lds[slot];
                const float w    = w_lds[slot];
                const uint4 hv   = *reinterpret_cast<const uint4*>(
                    hlin + (size_t)srcj * 32 + cl * 8);
                dsum += w;
                acc[0] = fmaf(w, bflo(hv.x), acc[0]);
                acc[1] = fmaf(w, bfhi(hv.x), acc[1]);
                acc[2] = fmaf(w, bflo(hv.y), acc[2]);
                acc[3] = fmaf(w, bfhi(hv.y), acc[3]);
                acc[4] = fmaf(w, bflo(hv.z), acc[4]);
                acc[5] = fmaf(w, bfhi(hv.z), acc[5]);
                acc[6] = fmaf(w, bflo(hv.w), acc[6]);
                acc[7] = fmaf(w, bfhi(hv.w), acc[7]);
            }
        }
        // LDS reuse across chunks is safe: wave-synchronous (each lane's next
        // ds_write happens after its own ds_reads of the previous chunk).
    }

    if (F_OUT == 128) {
#pragma unroll
        for (int t = 0; t < 8; ++t) {
            acc[t] += __shfl_xor(acc[t], 16, 64);
            acc[t] += __shfl_xor(acc[t], 32, 64);
        }
        dsum += __shfl_xor(dsum, 16, 64);
        dsum += __shfl_xor(dsum, 32, 64);
        if (lane < 16) {
            const float rinv = 1.f / (dsum + 1e-16f);
            const int c0 = lane * 8;
            float v[8];
#pragma unroll
            for (int t = 0; t < 8; ++t) v[t] = elu(fmaf(acc[t], rinv, bias[c0 + t]));
            uint4 pk;
            pk.x = f2bf2(v[0], v[1]);
            pk.y = f2bf2(v[2], v[3]);
            pk.z = f2bf2(v[4], v[5]);
            pk.w = f2bf2(v[6], v[7]);
            *reinterpret_cast<uint4*>((unsigned short*)out_v + (size_t)d * 128 + c0) = pk;
        }
    } else {
#pragma unroll
        for (int t = 0; t < 8; ++t) {
            acc[t] += __shfl_xor(acc[t], 4, 64);
            acc[t] += __shfl_xor(acc[t], 8, 64);
            acc[t] += __shfl_xor(acc[t], 16, 64);
            acc[t] += __shfl_xor(acc[t], 32, 64);
        }
        dsum += __shfl_xor(dsum, 4, 64);
        dsum += __shfl_xor(dsum, 8, 64);
        dsum += __shfl_xor(dsum, 16, 64);
        dsum += __shfl_xor(dsum, 32, 64);
        if (lane < 4) {
            const float rinv = 1.f / (dsum + 1e-16f);
            const int c0 = lane * 8;
            float v[8];
#pragma unroll
            for (int t = 0; t < 8; ++t) v[t] = elu(fmaf(acc[t], rinv, bias[c0 + t]));
            float* op = (float*)out_v + (size_t)d * 32 + c0;
            *reinterpret_cast<float4*>(op)     = make_float4(v[0], v[1], v[2], v[3]);
            *reinterpret_cast<float4*>(op + 4) = make_float4(v[4], v[5], v[6], v[7]);
        }
    }
}

// ---------------------------------------------------------------------------
__global__ __launch_bounds__(256) void pool_fc_kernel(
    const float* __restrict__ h4, const int* __restrict__ batch,
    const float* __restrict__ fcW, const float* __restrict__ fcb,
    float* __restrict__ out)
{
    const int g = blockIdx.x;
    __shared__ int sb, se;
    if (threadIdx.x == 0) {
        int lo = 0, hi = NN;
        while (lo < hi) { int mid = (lo + hi) >> 1; if (batch[mid] < g) lo = mid + 1; else hi = mid; }
        sb = lo;
        lo = sb; hi = NN;
        while (lo < hi) { int mid = (lo + hi) >> 1; if (batch[mid] < g + 1) lo = mid + 1; else hi = mid; }
        se = lo;
    }
    __syncthreads();
    const int s = sb, e = se;

    const int c  = threadIdx.x & 31;
    const int rg = threadIdx.x >> 5;
    float acc = 0.f;
    for (int n = s + rg; n < e; n += 8)
        acc += h4[(size_t)n * HIDC + c];

    __shared__ float red[8][32];
    red[rg][c] = acc;
    __syncthreads();
    __shared__ float pooled_s[32];
    if (threadIdx.x < 32) {
        float v = 0.f;
#pragma unroll
        for (int r = 0; r < 8; ++r) v += red[r][threadIdx.x];
        pooled_s[threadIdx.x] = v / fmaxf((float)(e - s), 1.f);
    }
    __syncthreads();
    if (threadIdx.x < OUTC) {
        const int o = threadIdx.x;
        float a2 = fcb[o];
#pragma unroll
        for (int cc = 0; cc < HIDC; ++cc)
            a2 = fmaf(pooled_s[cc], fcW[cc * OUTC + o], a2);
        out[g * OUTC + o] = a2;
    }
}

// ---------------------------------------------------------------------------
extern "C" void kernel_launch(void* const* d_in, const int* in_sizes, int n_in,
                              void* d_out, int out_size, void* d_ws, size_t ws_size,
                              hipStream_t stream)
{
    const float* x     = (const float*)d_in[0];
    const int*   ei    = (const int*)d_in[1];
    const int*   batch = (const int*)d_in[2];
    const float* W1  = (const float*)d_in[3];
    const float* a1s = (const float*)d_in[4];
    const float* a1d = (const float*)d_in[5];
    const float* b1  = (const float*)d_in[6];
    const float* W2  = (const float*)d_in[7];
    const float* a2s = (const float*)d_in[8];
    const float* a2d = (const float*)d_in[9];
    const float* b2  = (const float*)d_in[10];
    const float* W3  = (const float*)d_in[11];
    const float* a3s = (const float*)d_in[12];
    const float* a3d = (const float*)d_in[13];
    const float* b3  = (const float*)d_in[14];
    const float* W4  = (const float*)d_in[15];
    const float* a4s = (const float*)d_in[16];
    const float* a4d = (const float*)d_in[17];
    const float* b4  = (const float*)d_in[18];
    const float* fcW = (const float*)d_in[19];
    const float* fcb = (const float*)d_in[20];
    float* out = (float*)d_out;

    // workspace layout (blocksorted now UN-aliased from hb: fused launch
    // writes both concurrently; bufF still aliases xb)
    unsigned short* xb = (unsigned short*)d_ws;                 // NNPAD*128 bf16
    unsigned short* hb = xb + (size_t)NNPAD * 128;              // NNPAD*128 bf16
    float* asb  = (float*)(hb + (size_t)NNPAD * 128);           // N*4
    float* adb  = asb + (size_t)NN * 4;                         // N*4
    int*   offs    = (int*)(adb + (size_t)NN * 4);              // N+1
    unsigned int* csrpack = (unsigned int*)(offs + NN + 1);     // E+N (src|dst<<16)
    int*   boffs  = (int*)(csrpack + ETOT);                     // NBLK*(NRANGE+1)
    int*   rbase  = boffs + NBLK * (NRANGE + 1);                // NRANGE+1
    int*   rtot   = rbase + NRANGE + 1;                         // NRANGE
    unsigned short* wtg = (unsigned short*)(rtot + NRANGE);     // 4*144*128 bf16
    unsigned int* blocksorted = (unsigned int*)(wtg + 4 * 144 * 128); // NBLK*EPB
    float* bufF = (float*)xb;                                   // N*32 f32 (alias)

    // ---- prep (W+ahat -> prepacked bf16 swizzled images), needed by gemm1 ----
    prep_kernel<<<4, 256, 0, stream>>>(W1, a1s, a1d, W2, a2s, a2d,
                                       W3, a3s, a3d, W4, a4s, a4d, wtg);

    constexpr int GEMM_GRID = NNPAD / 128;      // 391
    constexpr int AGG_GRID  = (NN + 3) / 4;     // 12500
    constexpr size_t WSTRIDE = 144 * 128;

    // ---- fused: CSR local_sort (196 blocks) || layer-1 GEMM (391 blocks) ----
    fused_ls_gemm1_kernel<<<NBLK + GEMM_GRID, 256, 0, stream>>>(
        ei, blocksorted, boffs, x, wtg + 0 * WSTRIDE, hb, asb, adb);

    // ---- rest of CSR build ----
    rtot_kernel<<<(NRANGE + 3) / 4, 256, 0, stream>>>(boffs, rtot);
    rscan_kernel<<<1, 512, 0, stream>>>(rtot, rbase);
    phaseB_kernel<<<NRANGE, 256, 0, stream>>>(boffs, blocksorted, rbase, offs, csrpack);

    // ---- layer 1 aggregate ----
    aggregate_kernel<4, 128, true><<<AGG_GRID, 256, 0, stream>>>(hb, asb, adb, offs, csrpack, b1, xb);
    // ---- layer 2 ----
    gemm_mfma_kernel<128, 4><<<GEMM_GRID, 256, 0, stream>>>(xb, wtg + 1 * WSTRIDE, hb, asb, adb);
    aggregate_kernel<4, 128, true><<<AGG_GRID, 256, 0, stream>>>(hb, asb, adb, offs, csrpack, b2, xb);
    // ---- layer 3 ----
    gemm_mfma_kernel<128, 4><<<GEMM_GRID, 256, 0, stream>>>(xb, wtg + 2 * WSTRIDE, hb, asb, adb);
    aggregate_kernel<4, 128, true><<<AGG_GRID, 256, 0, stream>>>(hb, asb, adb, offs, csrpack, b3, xb);
    // ---- layer 4 (heads=1, 32 ch, f32 out) ----
    gemm_mfma_kernel<32, 1><<<GEMM_GRID, 256, 0, stream>>>(xb, wtg + 3 * WSTRIDE, hb, asb, adb);
    aggregate_kernel<1, 32, false><<<AGG_GRID, 256, 0, stream>>>(hb, asb, adb, offs, csrpack, b4, bufF);

    // ---- fused mean pool + FC ----
    pool_fc_kernel<<<GG, 256, 0, stream>>>(bufF, batch, fcW, fcb, out);
}